// Round 2
// baseline (566.419 us; speedup 1.0000x reference)
//
#include <hip/hip_runtime.h>

#define N_NODES 10000
#define FDIM 64
#define UDIM 128
#define BATCH 8
#define NEDGE 160000
#define NB 80000  /* N_NODES*BATCH */

typedef unsigned int u32;
typedef unsigned short u16;
typedef __attribute__((ext_vector_type(8))) short short8;
typedef __attribute__((ext_vector_type(4))) float float4v;

__device__ __forceinline__ float bf2f(u16 h) { return __uint_as_float(((u32)h) << 16); }
__device__ __forceinline__ u16 f2bf(float f) {
    u32 u = __float_as_uint(f);
    return (u16)((u + 0x7fffu + ((u >> 16) & 1u)) >> 16);
}
__device__ __forceinline__ float lo16(u32 u) { return __uint_as_float(u << 16); }
__device__ __forceinline__ float hi16(u32 u) { return __uint_as_float(u & 0xffff0000u); }
__device__ __forceinline__ u32 pack2(float a, float b) {
    return (u32)f2bf(a) | (((u32)f2bf(b)) << 16);
}

// ---------------- CSR build ----------------
__global__ void count_kernel(const int* __restrict__ rows, const int* __restrict__ cols,
                             int* __restrict__ cnt1, int* __restrict__ cnt2) {
    int e = blockIdx.x * 256 + threadIdx.x;
    if (e < NEDGE) {
        atomicAdd(&cnt1[cols[e]], 1);  // support1: dst = cols
        atomicAdd(&cnt2[rows[e]], 1);  // support2: dst = rows
    }
}

// single block, 256 threads; exclusive scan of both count arrays -> rowptr + cursor
__global__ void scan_kernel(int* __restrict__ cnt1, int* __restrict__ cnt2,
                            int* __restrict__ rowptr1, int* __restrict__ rowptr2) {
    __shared__ int lds[256];
    int t = threadIdx.x;
    const int CH = (N_NODES + 255) / 256;  // 40
    for (int s = 0; s < 2; s++) {
        int* cnt = s ? cnt2 : cnt1;          // cursor aliases cnt (overwritten)
        int* rp = s ? rowptr2 : rowptr1;
        __syncthreads();
        int base = t * CH;
        int sum = 0;
        for (int i = 0; i < CH; i++) {
            int idx = base + i;
            sum += (idx < N_NODES) ? cnt[idx] : 0;
        }
        lds[t] = sum;
        __syncthreads();
        for (int off = 1; off < 256; off <<= 1) {
            int add = (t >= off) ? lds[t - off] : 0;
            __syncthreads();
            lds[t] += add;
            __syncthreads();
        }
        int excl = lds[t] - sum;
        int run = excl;
        for (int i = 0; i < CH; i++) {
            int idx = base + i;
            if (idx < N_NODES) {
                int c = cnt[idx];
                rp[idx] = run;
                cnt[idx] = run;  // cursor init
                run += c;
            }
        }
        if (t == 255) rp[N_NODES] = run;  // == NEDGE
    }
}

__global__ void scatter_kernel(const int* __restrict__ rows, const int* __restrict__ cols,
                               const float* __restrict__ w1, const float* __restrict__ w2,
                               int* __restrict__ cur1, int* __restrict__ cur2,
                               int2* __restrict__ edges1, int2* __restrict__ edges2) {
    int e = blockIdx.x * 256 + threadIdx.x;
    if (e < NEDGE) {
        int r = rows[e], c = cols[e];
        int p1 = atomicAdd(&cur1[c], 1);
        edges1[p1] = make_int2(r, __float_as_int(w1[e]));
        int p2 = atomicAdd(&cur2[r], 1);
        edges2[p2] = make_int2(c, __float_as_int(w2[e]));
    }
}

// ---------------- transpose y (B,N,F) fp32 -> X0 node-major bf16 (n*8+b, 64) --------
__global__ void transpose_kernel(const float2* __restrict__ y, u32* __restrict__ X0) {
    int idx = blockIdx.x * 256 + threadIdx.x;  // over NB*32 packed-u32 outputs
    if (idx >= NB * 32) return;
    int fh = idx & 31;
    int rb = idx >> 5;
    int b = rb & 7;
    int n = rb >> 3;
    float2 v = y[((size_t)b * N_NODES + n) * 32 + fh];
    X0[idx] = pack2(v.x, v.y);
}

// ---------------- SpMM gather: out[n] = alpha*sum_e w*Xin[src] (+ beta*Xprev[n]) ------
template <int VU>  // uints per node: 256 (width 512 bf16) or 512 (width 1024)
__global__ __launch_bounds__(256) void spmm_kernel(
    const u32* __restrict__ Xin, const u32* __restrict__ Xprev,
    const int* __restrict__ rowptr, const int2* __restrict__ edges,
    u32* __restrict__ Xout, float alpha, float beta) {
    constexpr int PT = VU / 256;
    int n = blockIdx.x;
    int t = threadIdx.x;
    float acc[2 * PT];
#pragma unroll
    for (int i = 0; i < 2 * PT; i++) acc[i] = 0.f;
    int e0 = rowptr[n], e1 = rowptr[n + 1];
    int j = e0;
    for (; j + 1 < e1; j += 2) {  // 2-way unroll for load ILP
        int2 ea = edges[j];
        int2 eb = edges[j + 1];
        float wa = __int_as_float(ea.y);
        float wb = __int_as_float(eb.y);
        const u32* sa = Xin + (size_t)ea.x * VU + t;
        const u32* sb = Xin + (size_t)eb.x * VU + t;
#pragma unroll
        for (int p = 0; p < PT; p++) {
            u32 ua = sa[p * 256];
            u32 ub = sb[p * 256];
            acc[2 * p]     += wa * lo16(ua) + wb * lo16(ub);
            acc[2 * p + 1] += wa * hi16(ua) + wb * hi16(ub);
        }
    }
    if (j < e1) {
        int2 e = edges[j];
        float w = __int_as_float(e.y);
        const u32* src = Xin + (size_t)e.x * VU + t;
#pragma unroll
        for (int p = 0; p < PT; p++) {
            u32 u = src[p * 256];
            acc[2 * p]     += w * lo16(u);
            acc[2 * p + 1] += w * hi16(u);
        }
    }
    u32* outp = Xout + (size_t)n * VU + t;
#pragma unroll
    for (int p = 0; p < PT; p++) {
        float a = alpha * acc[2 * p];
        float b2 = alpha * acc[2 * p + 1];
        if (beta != 0.f) {
            u32 u = Xprev[(size_t)n * VU + t + p * 256];
            a += beta * lo16(u);
            b2 += beta * hi16(u);
        }
        outp[p * 256] = pack2(a, b2);
    }
}

// ---------------- B pack: Bp[ks][ct][lane][8] = bf16(W[(k%FIN)*5 + k/FIN][col]) -----
__global__ void bpack_kernel(const float* __restrict__ W, u16* __restrict__ out,
                             int FIN, int NOUT, int total) {
    int idx = blockIdx.x * 256 + threadIdx.x;
    if (idx >= total) return;
    int j = idx & 7;
    int lane = (idx >> 3) & 63;
    int rest = idx >> 9;
    int CT = NOUT >> 4;
    int ct = rest % CT;
    int ks = rest / CT;
    int k = ks * 32 + (lane >> 4) * 8 + j;
    int col = ct * 16 + (lane & 15);
    int wrow = (k % FIN) * 5 + (k / FIN);
    out[idx] = f2bf(W[wrow * NOUT + col]);
}

// ---------------- MFMA GEMM: C(80000 x NOUT) = A(80000 x 5*FIN) @ Bp ----------------
struct Slabs { const u16* p[5]; };

template <int FIN, int NOUT, int ACT>  // ACT: 1=sigmoid->Cout(bf16), 2=tanh->Cout(bf16), 3=tanh, -theta*c -> outF(fp32)
__global__ __launch_bounds__(256) void gemm_kernel(
    Slabs A, const u16* __restrict__ Bp, const float* __restrict__ bias,
    u16* __restrict__ Cout, const u16* __restrict__ theta, float* __restrict__ outF) {
    constexpr int K = 5 * FIN;
    constexpr int KS = K / 32;
    constexpr int CT = NOUT / 16;
    int lane = threadIdx.x & 63;
    int wave = threadIdx.x >> 6;
    int rowBase = blockIdx.x * 128 + wave * 32;
    int mrow = lane & 15;
    int kq = lane >> 4;

    float4v acc[2][CT];
#pragma unroll
    for (int s = 0; s < 2; s++)
#pragma unroll
        for (int c = 0; c < CT; c++) acc[s][c] = (float4v){0.f, 0.f, 0.f, 0.f};

    for (int ks = 0; ks < KS; ks++) {
        int k = ks * 32 + kq * 8;
        int m = k / FIN;        // uniform within ks (32-chunks don't cross 64/128 slabs)
        int koff = k % FIN;
        const u16* abase = A.p[m] + (size_t)(rowBase + mrow) * FIN + koff;
        short8 a0 = *(const short8*)(abase);
        short8 a1 = *(const short8*)(abase + 16 * FIN);
        const u16* bbase = Bp + ((size_t)(ks * CT) * 64 + lane) * 8;
#pragma unroll
        for (int ct = 0; ct < CT; ct++) {
            short8 b = *(const short8*)(bbase + (size_t)ct * 64 * 8);
            acc[0][ct] = __builtin_amdgcn_mfma_f32_16x16x32_bf16(a0, b, acc[0][ct], 0, 0, 0);
            acc[1][ct] = __builtin_amdgcn_mfma_f32_16x16x32_bf16(a1, b, acc[1][ct], 0, 0, 0);
        }
    }

#pragma unroll
    for (int sub = 0; sub < 2; sub++) {
        int rowq = rowBase + sub * 16 + kq * 4;
#pragma unroll
        for (int ct = 0; ct < CT; ct++) {
            int col = ct * 16 + mrow;
            float bsv = bias[col];
#pragma unroll
            for (int i = 0; i < 4; i++) {
                float v = acc[sub][ct][i] + bsv;
                int r = rowq + i;
                if (ACT == 1) {
                    v = 1.f / (1.f + __expf(-v));
                    Cout[(size_t)r * NOUT + col] = f2bf(v);
                } else if (ACT == 2) {
                    v = 1.f - 2.f / (__expf(2.f * v) + 1.f);
                    Cout[(size_t)r * NOUT + col] = f2bf(v);
                } else {
                    v = 1.f - 2.f / (__expf(2.f * v) + 1.f);
                    float th = bf2f(theta[(size_t)r * 64 + col]);
                    float o = -th * v;
                    int n = r >> 3, b = r & 7;
                    outF[(size_t)b * (N_NODES * 64) + (size_t)n * 64 + col] = o;
                }
            }
        }
    }
}

// ---------------- launch ----------------
extern "C" void kernel_launch(void* const* d_in, const int* in_sizes, int n_in,
                              void* d_out, int out_size, void* d_ws, size_t ws_size,
                              hipStream_t stream) {
    const float* y     = (const float*)d_in[0];
    const float* W_lat = (const float*)d_in[1];
    const float* b_lat = (const float*)d_in[2];
    const float* W_units = (const float*)d_in[3];
    const float* b_units = (const float*)d_in[4];
    const float* W_final = (const float*)d_in[5];
    const float* sup1w = (const float*)d_in[6];
    const float* sup2w = (const float*)d_in[7];
    const int* rows    = (const int*)d_in[8];
    const int* cols    = (const int*)d_in[9];
    float* out = (float*)d_out;

    char* ws = (char*)d_ws;
    size_t off = 0;
    auto alloc = [&](size_t bytes) -> void* {
        void* p = ws + off;
        off += (bytes + 511) & ~(size_t)511;
        return p;
    };
    int* rowptr1 = (int*)alloc((N_NODES + 1) * 4);
    int* rowptr2 = (int*)alloc((N_NODES + 1) * 4);
    int* cnt = (int*)alloc((size_t)2 * N_NODES * 4);  // cnt1|cnt2, reused as cursors
    int* cnt1 = cnt;
    int* cnt2 = cnt + N_NODES;
    int2* edges1 = (int2*)alloc((size_t)NEDGE * 8);
    int2* edges2 = (int2*)alloc((size_t)NEDGE * 8);
    u16* bpk1 = (u16*)alloc((size_t)320 * 64 * 2);
    u16* bpk2 = (u16*)alloc((size_t)320 * 128 * 2);
    u16* bpk3 = (u16*)alloc((size_t)640 * 64 * 2);
    u16* theta = (u16*)alloc((size_t)NB * 64 * 2);
    u16* S = (u16*)alloc((size_t)5 * NB * 64 * 2);  // S0..S4, each NB*64
    u16* H0 = (u16*)alloc((size_t)NB * 128 * 2);
    u16* H3 = (u16*)alloc((size_t)NB * 128 * 2);
    u16* H4 = (u16*)alloc((size_t)NB * 128 * 2);
    u16* H1 = S;                        // overlay: S dead after gemm1/gemm2
    u16* H2 = S + (size_t)NB * 128;

    const size_t SLAB = (size_t)NB * 64;  // u16 elems per x-slab

    hipMemsetAsync(cnt, 0, (size_t)2 * N_NODES * 4, stream);
    count_kernel<<<(NEDGE + 255) / 256, 256, 0, stream>>>(rows, cols, cnt1, cnt2);
    scan_kernel<<<1, 256, 0, stream>>>(cnt1, cnt2, rowptr1, rowptr2);
    scatter_kernel<<<(NEDGE + 255) / 256, 256, 0, stream>>>(rows, cols, sup1w, sup2w,
                                                            cnt1, cnt2, edges1, edges2);
    transpose_kernel<<<(NB * 32 + 255) / 256, 256, 0, stream>>>((const float2*)y, (u32*)S);

    bpack_kernel<<<(320 * 64 + 255) / 256, 256, 0, stream>>>(W_lat, bpk1, 64, 64, 320 * 64);
    bpack_kernel<<<(320 * 128 + 255) / 256, 256, 0, stream>>>(W_units, bpk2, 64, 128, 320 * 128);
    bpack_kernel<<<(640 * 64 + 255) / 256, 256, 0, stream>>>(W_final, bpk3, 128, 64, 640 * 64);

    // diffusion series on x (width 512 bf16 = 256 uints)
    const u32* S0 = (const u32*)S;
    spmm_kernel<256><<<N_NODES, 256, 0, stream>>>(S0, S0, rowptr1, edges1,
                                                  (u32*)(S + 1 * SLAB), 1.f, 0.f);
    spmm_kernel<256><<<N_NODES, 256, 0, stream>>>((const u32*)(S + 1 * SLAB), S0, rowptr1, edges1,
                                                  (u32*)(S + 2 * SLAB), 2.f, -1.f);
    spmm_kernel<256><<<N_NODES, 256, 0, stream>>>(S0, S0, rowptr2, edges2,
                                                  (u32*)(S + 3 * SLAB), 1.f, 0.f);
    spmm_kernel<256><<<N_NODES, 256, 0, stream>>>((const u32*)(S + 3 * SLAB), S0, rowptr2, edges2,
                                                  (u32*)(S + 4 * SLAB), 2.f, -1.f);

    Slabs SX;
    for (int m = 0; m < 5; m++) SX.p[m] = S + (size_t)m * SLAB;
    // theta = sigmoid(X @ W_lat' + b_lat)
    gemm_kernel<64, 64, 1><<<625, 256, 0, stream>>>(SX, bpk1, b_lat, theta, nullptr, nullptr);
    // H0 = tanh(X @ W_units' + b_units)
    gemm_kernel<64, 128, 2><<<625, 256, 0, stream>>>(SX, bpk2, b_units, H0, nullptr, nullptr);

    // diffusion series on h (width 1024 bf16 = 512 uints)
    spmm_kernel<512><<<N_NODES, 256, 0, stream>>>((const u32*)H0, (const u32*)H0, rowptr1, edges1,
                                                  (u32*)H1, 1.f, 0.f);
    spmm_kernel<512><<<N_NODES, 256, 0, stream>>>((const u32*)H1, (const u32*)H0, rowptr1, edges1,
                                                  (u32*)H2, 2.f, -1.f);
    spmm_kernel<512><<<N_NODES, 256, 0, stream>>>((const u32*)H0, (const u32*)H0, rowptr2, edges2,
                                                  (u32*)H3, 1.f, 0.f);
    spmm_kernel<512><<<N_NODES, 256, 0, stream>>>((const u32*)H3, (const u32*)H0, rowptr2, edges2,
                                                  (u32*)H4, 2.f, -1.f);

    Slabs SH;
    SH.p[0] = H0; SH.p[1] = H1; SH.p[2] = H2; SH.p[3] = H3; SH.p[4] = H4;
    // out = -theta * tanh(Xh @ W_final' + b_lat)
    gemm_kernel<128, 64, 3><<<625, 256, 0, stream>>>(SH, bpk3, b_lat, nullptr, theta, out);
}

// Round 3
// 459.076 us; speedup vs baseline: 1.2338x; 1.2338x over previous
//
#include <hip/hip_runtime.h>

#define N_NODES 10000
#define FDIM 64
#define UDIM 128
#define BATCH 8
#define NEDGE 160000
#define NB 80000  /* N_NODES*BATCH */
#define SCAN_CH 40 /* 256-wide chunks per array */

typedef unsigned int u32;
typedef unsigned short u16;
typedef __attribute__((ext_vector_type(8))) short short8;
typedef __attribute__((ext_vector_type(4))) float float4v;

__device__ __forceinline__ float bf2f(u16 h) { return __uint_as_float(((u32)h) << 16); }
__device__ __forceinline__ u16 f2bf(float f) {
    u32 u = __float_as_uint(f);
    return (u16)((u + 0x7fffu + ((u >> 16) & 1u)) >> 16);
}
__device__ __forceinline__ float lo16(u32 u) { return __uint_as_float(u << 16); }
__device__ __forceinline__ float hi16(u32 u) { return __uint_as_float(u & 0xffff0000u); }
__device__ __forceinline__ u32 pack2(float a, float b) {
    return (u32)f2bf(a) | (((u32)f2bf(b)) << 16);
}
__device__ __forceinline__ float fast_tanh(float v) {
    return 1.f - 2.f / (__expf(2.f * v) + 1.f);
}

// ---------------- CSR build ----------------
__global__ void count_kernel(const int* __restrict__ rows, const int* __restrict__ cols,
                             int* __restrict__ cnt1, int* __restrict__ cnt2) {
    int e = blockIdx.x * 256 + threadIdx.x;
    if (e < NEDGE) {
        atomicAdd(&cnt1[cols[e]], 1);  // support1: dst = cols
        atomicAdd(&cnt2[rows[e]], 1);  // support2: dst = rows
    }
}

// 80 blocks: per-chunk sums (arr = b/40, chunk = b%40)
__global__ void blocksum_kernel(const int* __restrict__ cnt, int* __restrict__ bsums) {
    __shared__ int red[4];
    int arr = blockIdx.x / SCAN_CH;
    int c = blockIdx.x % SCAN_CH;
    int idx = c * 256 + threadIdx.x;
    int v = (idx < N_NODES) ? cnt[arr * N_NODES + idx] : 0;
#pragma unroll
    for (int off = 32; off; off >>= 1) v += __shfl_down(v, off, 64);
    int wv = threadIdx.x >> 6, ln = threadIdx.x & 63;
    if (ln == 0) red[wv] = v;
    __syncthreads();
    if (threadIdx.x == 0) bsums[blockIdx.x] = red[0] + red[1] + red[2] + red[3];
}

// 1 block, 128 threads: exclusive scan of the 40 block-sums per array
__global__ void scanmid_kernel(int* __restrict__ bsums, int* __restrict__ rowptr1,
                               int* __restrict__ rowptr2) {
    __shared__ int lds[128];
    int t = threadIdx.x;
    int seg = t >> 6, pos = t & 63;
    int v = (pos < SCAN_CH) ? bsums[seg * SCAN_CH + pos] : 0;
    lds[t] = v;
    __syncthreads();
    for (int off = 1; off < 64; off <<= 1) {
        int add = (pos >= off) ? lds[t - off] : 0;
        __syncthreads();
        lds[t] += add;
        __syncthreads();
    }
    if (pos < SCAN_CH) bsums[seg * SCAN_CH + pos] = pos ? lds[t - 1] : 0;
    if (t == 0) { rowptr1[N_NODES] = NEDGE; rowptr2[N_NODES] = NEDGE; }
}

// 80 blocks: local exclusive scan + block offset -> rowptr + cursor (in-place in cnt)
__global__ void scanapply_kernel(int* __restrict__ cnt, const int* __restrict__ bsums,
                                 int* __restrict__ rowptr1, int* __restrict__ rowptr2) {
    __shared__ int lds[256];
    int arr = blockIdx.x / SCAN_CH;
    int c = blockIdx.x % SCAN_CH;
    int idx = c * 256 + threadIdx.x;
    bool ok = idx < N_NODES;
    int v = ok ? cnt[arr * N_NODES + idx] : 0;
    int t = threadIdx.x;
    lds[t] = v;
    __syncthreads();
    for (int off = 1; off < 256; off <<= 1) {
        int add = (t >= off) ? lds[t - off] : 0;
        __syncthreads();
        lds[t] += add;
        __syncthreads();
    }
    int excl = lds[t] - v + bsums[blockIdx.x];
    if (ok) {
        int* rp = arr ? rowptr2 : rowptr1;
        rp[idx] = excl;
        cnt[arr * N_NODES + idx] = excl;  // cursor
    }
}

__global__ void scatter_kernel(const int* __restrict__ rows, const int* __restrict__ cols,
                               const float* __restrict__ w1, const float* __restrict__ w2,
                               int* __restrict__ cur1, int* __restrict__ cur2,
                               int2* __restrict__ edges1, int2* __restrict__ edges2) {
    int e = blockIdx.x * 256 + threadIdx.x;
    if (e < NEDGE) {
        int r = rows[e], c = cols[e];
        int p1 = atomicAdd(&cur1[c], 1);
        edges1[p1] = make_int2(r, __float_as_int(w1[e]));
        int p2 = atomicAdd(&cur2[r], 1);
        edges2[p2] = make_int2(c, __float_as_int(w2[e]));
    }
}

// ---------------- transpose y (B,N,F) fp32 -> X0 node-major bf16 (n*8+b, 64) --------
__global__ void transpose_kernel(const float2* __restrict__ y, u32* __restrict__ X0) {
    int idx = blockIdx.x * 256 + threadIdx.x;  // over NB*32 packed-u32 outputs
    if (idx >= NB * 32) return;
    int fh = idx & 31;
    int rb = idx >> 5;
    int b = rb & 7;
    int n = rb >> 3;
    float2 v = y[((size_t)b * N_NODES + n) * 32 + fh];
    X0[idx] = pack2(v.x, v.y);
}

// ---------------- SpMM gather ----------------
// MODE 0: out = alpha*(S@Xin) + beta*Xprev   (bf16 out)
// MODE 1: outF = -theta * tanh(Xprev + Xprev2 + S@Xin)  (fp32, (B,N,64) layout)
template <int VU, int MODE>
__global__ __launch_bounds__(256) void spmm_kernel(
    const u32* __restrict__ Xin, const u32* __restrict__ Xprev,
    const int* __restrict__ rowptr, const int2* __restrict__ edges,
    u32* __restrict__ Xout, float alpha, float beta,
    const u32* __restrict__ Xprev2, const u32* __restrict__ theta,
    float* __restrict__ outF) {
    constexpr int PT = VU / 256;
    int n = blockIdx.x;
    int t = threadIdx.x;
    float acc[2 * PT];
#pragma unroll
    for (int i = 0; i < 2 * PT; i++) acc[i] = 0.f;
    int e0 = rowptr[n], e1 = rowptr[n + 1];
    int j = e0;
    for (; j + 1 < e1; j += 2) {  // 2-way unroll for load ILP
        int2 ea = edges[j];
        int2 eb = edges[j + 1];
        float wa = __int_as_float(ea.y);
        float wb = __int_as_float(eb.y);
        const u32* sa = Xin + (size_t)ea.x * VU + t;
        const u32* sb = Xin + (size_t)eb.x * VU + t;
#pragma unroll
        for (int p = 0; p < PT; p++) {
            u32 ua = sa[p * 256];
            u32 ub = sb[p * 256];
            acc[2 * p]     += wa * lo16(ua) + wb * lo16(ub);
            acc[2 * p + 1] += wa * hi16(ua) + wb * hi16(ub);
        }
    }
    if (j < e1) {
        int2 e = edges[j];
        float w = __int_as_float(e.y);
        const u32* src = Xin + (size_t)e.x * VU + t;
#pragma unroll
        for (int p = 0; p < PT; p++) {
            u32 u = src[p * 256];
            acc[2 * p]     += w * lo16(u);
            acc[2 * p + 1] += w * hi16(u);
        }
    }
    if (MODE == 0) {
        u32* outp = Xout + (size_t)n * VU + t;
#pragma unroll
        for (int p = 0; p < PT; p++) {
            float a = alpha * acc[2 * p];
            float b2 = alpha * acc[2 * p + 1];
            if (beta != 0.f) {
                u32 u = Xprev[(size_t)n * VU + t + p * 256];
                a += beta * lo16(u);
                b2 += beta * hi16(u);
            }
            outp[p * 256] = pack2(a, b2);
        }
    } else {
        // VU==256: u32 t covers (b = t>>5, f0 = (t&31)*2)
        size_t ri = (size_t)n * 256 + t;
        u32 q = Xprev[ri];
        u32 u1 = Xprev2[ri];
        u32 th = theta[ri];
        float vlo = fast_tanh(lo16(q) + lo16(u1) + acc[0]);
        float vhi = fast_tanh(hi16(q) + hi16(u1) + acc[1]);
        float2 o;
        o.x = -lo16(th) * vlo;
        o.y = -hi16(th) * vhi;
        int b = t >> 5;
        int f0 = (t & 31) * 2;
        *(float2*)(outF + (size_t)b * (N_NODES * 64) + (size_t)n * 64 + f0) = o;
    }
}

// ---------------- B pack (x-side): Bp[ks][ct][lane][8] = bf16(W[(k%FIN)*5+k/FIN][col])
__global__ void bpack_kernel(const float* __restrict__ W, u16* __restrict__ out,
                             int FIN, int NOUT, int total) {
    int idx = blockIdx.x * 256 + threadIdx.x;
    if (idx >= total) return;
    int j = idx & 7;
    int lane = (idx >> 3) & 63;
    int rest = idx >> 9;
    int CT = NOUT >> 4;
    int ct = rest % CT;
    int ks = rest / CT;
    int k = ks * 32 + (lane >> 4) * 8 + j;
    int col = ct * 16 + (lane & 15);
    int wrow = (k % FIN) * 5 + (k / FIN);
    out[idx] = f2bf(W[wrow * NOUT + col]);
}

// B pack for P-GEMM: K=128 (hidden unit u), NOUT=320 (slot*64+j)
// slot0 = W_final[:,m=0] - [:,m=2] - [:,m=4]  (Q combine); slot m>=1 = W_final[:,m]
__global__ void bpackP_kernel(const float* __restrict__ W, u16* __restrict__ out) {
    int idx = blockIdx.x * 256 + threadIdx.x;  // total 4*20*64*8 = 40960
    if (idx >= 40960) return;
    int j8 = idx & 7;
    int lane = (idx >> 3) & 63;
    int rest = idx >> 9;  // ks*20 + ct
    int ct = rest % 20;
    int ks = rest / 20;
    int k = ks * 32 + (lane >> 4) * 8 + j8;  // u in [0,128)
    int col = ct * 16 + (lane & 15);         // [0,320)
    int slot = col >> 6, j = col & 63;
    float v;
    if (slot == 0)
        v = W[(k * 5 + 0) * 64 + j] - W[(k * 5 + 2) * 64 + j] - W[(k * 5 + 4) * 64 + j];
    else
        v = W[(k * 5 + slot) * 64 + j];
    out[idx] = f2bf(v);
}

// ---------------- MFMA GEMM: C(80000 x NOUT) = A(80000 x NM*FIN) @ Bp ----------------
struct Slabs { const u16* p[5]; };

// ACT: 0 = plain (+bias on slot0) -> 5 node-major 64-wide slabs (bf16)
//      1 = sigmoid -> Cout(bf16)   2 = tanh -> Cout(bf16)
template <int FIN, int NM, int NOUT, int ACT>
__global__ __launch_bounds__(256) void gemm_kernel(
    Slabs A, const u16* __restrict__ Bp, const float* __restrict__ bias,
    u16* __restrict__ Cout) {
    constexpr int K = NM * FIN;
    constexpr int KS = K / 32;
    constexpr int CT = NOUT / 16;
    int lane = threadIdx.x & 63;
    int wave = threadIdx.x >> 6;
    int rowBase = blockIdx.x * 128 + wave * 32;
    int mrow = lane & 15;
    int kq = lane >> 4;

    float4v acc[2][CT];
#pragma unroll
    for (int s = 0; s < 2; s++)
#pragma unroll
        for (int c = 0; c < CT; c++) acc[s][c] = (float4v){0.f, 0.f, 0.f, 0.f};

    for (int ks = 0; ks < KS; ks++) {
        int k = ks * 32 + kq * 8;
        int m = k / FIN;  // uniform within ks
        int koff = k % FIN;
        const u16* abase = A.p[m] + (size_t)(rowBase + mrow) * FIN + koff;
        short8 a0 = *(const short8*)(abase);
        short8 a1 = *(const short8*)(abase + 16 * FIN);
        const u16* bbase = Bp + ((size_t)(ks * CT) * 64 + lane) * 8;
#pragma unroll
        for (int ct = 0; ct < CT; ct++) {
            short8 b = *(const short8*)(bbase + (size_t)ct * 64 * 8);
            acc[0][ct] = __builtin_amdgcn_mfma_f32_16x16x32_bf16(a0, b, acc[0][ct], 0, 0, 0);
            acc[1][ct] = __builtin_amdgcn_mfma_f32_16x16x32_bf16(a1, b, acc[1][ct], 0, 0, 0);
        }
    }

#pragma unroll
    for (int sub = 0; sub < 2; sub++) {
        int rowq = rowBase + sub * 16 + kq * 4;
#pragma unroll
        for (int ct = 0; ct < CT; ct++) {
            int col = ct * 16 + mrow;
            float bsv;
            if (ACT == 0) bsv = (col < 64) ? bias[col] : 0.f;
            else bsv = bias[col];
#pragma unroll
            for (int i = 0; i < 4; i++) {
                float v = acc[sub][ct][i] + bsv;
                int r = rowq + i;
                if (ACT == 0) {
                    Cout[(size_t)(col >> 6) * ((size_t)NB * 64) + (size_t)r * 64 + (col & 63)] = f2bf(v);
                } else if (ACT == 1) {
                    v = 1.f / (1.f + __expf(-v));
                    Cout[(size_t)r * NOUT + col] = f2bf(v);
                } else {
                    Cout[(size_t)r * NOUT + col] = f2bf(fast_tanh(v));
                }
            }
        }
    }
}

// ---------------- launch ----------------
extern "C" void kernel_launch(void* const* d_in, const int* in_sizes, int n_in,
                              void* d_out, int out_size, void* d_ws, size_t ws_size,
                              hipStream_t stream) {
    const float* y     = (const float*)d_in[0];
    const float* W_lat = (const float*)d_in[1];
    const float* b_lat = (const float*)d_in[2];
    const float* W_units = (const float*)d_in[3];
    const float* b_units = (const float*)d_in[4];
    const float* W_final = (const float*)d_in[5];
    const float* sup1w = (const float*)d_in[6];
    const float* sup2w = (const float*)d_in[7];
    const int* rows    = (const int*)d_in[8];
    const int* cols    = (const int*)d_in[9];
    float* out = (float*)d_out;

    char* ws = (char*)d_ws;
    size_t off = 0;
    auto alloc = [&](size_t bytes) -> void* {
        void* p = ws + off;
        off += (bytes + 511) & ~(size_t)511;
        return p;
    };
    int* rowptr1 = (int*)alloc((N_NODES + 1) * 4);
    int* rowptr2 = (int*)alloc((N_NODES + 1) * 4);
    int* cnt = (int*)alloc((size_t)2 * N_NODES * 4);  // cnt1|cnt2, reused as cursors
    int* cnt1 = cnt;
    int* cnt2 = cnt + N_NODES;
    int* bsums = (int*)alloc(2 * SCAN_CH * 4);
    int2* edges1 = (int2*)alloc((size_t)NEDGE * 8);
    int2* edges2 = (int2*)alloc((size_t)NEDGE * 8);
    u16* bpk1 = (u16*)alloc((size_t)320 * 64 * 2);
    u16* bpk2 = (u16*)alloc((size_t)320 * 128 * 2);
    u16* bpkP = (u16*)alloc((size_t)40960 * 2);
    u16* theta = (u16*)alloc((size_t)NB * 64 * 2);
    u16* S = (u16*)alloc((size_t)5 * NB * 64 * 2);  // X-series; later overlaid by P/Q slabs
    u16* H0 = (u16*)alloc((size_t)NB * 128 * 2);
    u16* T1 = (u16*)alloc((size_t)NB * 64 * 2);
    u16* U1 = (u16*)alloc((size_t)NB * 64 * 2);
    u16* T2 = (u16*)alloc((size_t)NB * 64 * 2);
    u16* P = S;  // P/Q slabs overlay S (S dead after gemm1/gemm2)

    const size_t SLAB = (size_t)NB * 64;  // u16 elems per 64-wide slab

    hipMemsetAsync(cnt, 0, (size_t)2 * N_NODES * 4, stream);
    count_kernel<<<(NEDGE + 255) / 256, 256, 0, stream>>>(rows, cols, cnt1, cnt2);
    blocksum_kernel<<<2 * SCAN_CH, 256, 0, stream>>>(cnt, bsums);
    scanmid_kernel<<<1, 128, 0, stream>>>(bsums, rowptr1, rowptr2);
    scanapply_kernel<<<2 * SCAN_CH, 256, 0, stream>>>(cnt, bsums, rowptr1, rowptr2);
    scatter_kernel<<<(NEDGE + 255) / 256, 256, 0, stream>>>(rows, cols, sup1w, sup2w,
                                                            cnt1, cnt2, edges1, edges2);
    transpose_kernel<<<(NB * 32 + 255) / 256, 256, 0, stream>>>((const float2*)y, (u32*)S);

    bpack_kernel<<<(320 * 64 + 255) / 256, 256, 0, stream>>>(W_lat, bpk1, 64, 64, 320 * 64);
    bpack_kernel<<<(320 * 128 + 255) / 256, 256, 0, stream>>>(W_units, bpk2, 64, 128, 320 * 128);
    bpackP_kernel<<<(40960 + 255) / 256, 256, 0, stream>>>(W_final, bpkP);

    // diffusion series on x (width 512 bf16 = 256 uints)
    const u32* S0 = (const u32*)S;
    spmm_kernel<256, 0><<<N_NODES, 256, 0, stream>>>(S0, nullptr, rowptr1, edges1,
        (u32*)(S + 1 * SLAB), 1.f, 0.f, nullptr, nullptr, nullptr);
    spmm_kernel<256, 0><<<N_NODES, 256, 0, stream>>>((const u32*)(S + 1 * SLAB), S0, rowptr1, edges1,
        (u32*)(S + 2 * SLAB), 2.f, -1.f, nullptr, nullptr, nullptr);
    spmm_kernel<256, 0><<<N_NODES, 256, 0, stream>>>(S0, nullptr, rowptr2, edges2,
        (u32*)(S + 3 * SLAB), 1.f, 0.f, nullptr, nullptr, nullptr);
    spmm_kernel<256, 0><<<N_NODES, 256, 0, stream>>>((const u32*)(S + 3 * SLAB), S0, rowptr2, edges2,
        (u32*)(S + 4 * SLAB), 2.f, -1.f, nullptr, nullptr, nullptr);

    Slabs SX;
    for (int m = 0; m < 5; m++) SX.p[m] = S + (size_t)m * SLAB;
    // theta = sigmoid(X @ W_lat' + b_lat)
    gemm_kernel<64, 5, 64, 1><<<625, 256, 0, stream>>>(SX, bpk1, b_lat, theta);
    // H0 = tanh(X @ W_units' + b_units)
    gemm_kernel<64, 5, 128, 2><<<625, 256, 0, stream>>>(SX, bpk2, b_units, H0);

    // P-GEMM: [Q|P1|P2|P3|P4] = H0 @ bpkP (Q = P0-P2-P4 + b_lat), overlays S
    Slabs SH;
    SH.p[0] = H0;
    gemm_kernel<128, 1, 320, 0><<<625, 256, 0, stream>>>(SH, bpkP, b_lat, P);

    // h-side diffusion at width 512 (commuted): out = Q + S1(P1+2S1P2) + S2(P3+2S2P4)
    const u32* Q  = (const u32*)(P + 0 * SLAB);
    const u32* P1 = (const u32*)(P + 1 * SLAB);
    const u32* P2 = (const u32*)(P + 2 * SLAB);
    const u32* P3 = (const u32*)(P + 3 * SLAB);
    const u32* P4 = (const u32*)(P + 4 * SLAB);
    spmm_kernel<256, 0><<<N_NODES, 256, 0, stream>>>(P2, P1, rowptr1, edges1,
        (u32*)T1, 2.f, 1.f, nullptr, nullptr, nullptr);
    spmm_kernel<256, 0><<<N_NODES, 256, 0, stream>>>((const u32*)T1, nullptr, rowptr1, edges1,
        (u32*)U1, 1.f, 0.f, nullptr, nullptr, nullptr);
    spmm_kernel<256, 0><<<N_NODES, 256, 0, stream>>>(P4, P3, rowptr2, edges2,
        (u32*)T2, 2.f, 1.f, nullptr, nullptr, nullptr);
    // final: out = -theta * tanh(Q + U1 + S2@T2)
    spmm_kernel<256, 1><<<N_NODES, 256, 0, stream>>>((const u32*)T2, Q, rowptr2, edges2,
        nullptr, 1.f, 0.f, (const u32*)U1, (const u32*)theta, out);
}

// Round 4
// 385.421 us; speedup vs baseline: 1.4696x; 1.1911x over previous
//
#include <hip/hip_runtime.h>

#define N_NODES 10000
#define NEDGE 160000
#define NB 80000  /* N_NODES*BATCH */
#define SCAN_CH 40 /* 256-wide chunks per array */

typedef unsigned int u32;
typedef unsigned short u16;
typedef __attribute__((ext_vector_type(8))) short short8;
typedef __attribute__((ext_vector_type(4))) float float4v;

__device__ __forceinline__ float bf2f(u16 h) { return __uint_as_float(((u32)h) << 16); }
__device__ __forceinline__ u16 f2bf(float f) {
    u32 u = __float_as_uint(f);
    return (u16)((u + 0x7fffu + ((u >> 16) & 1u)) >> 16);
}
__device__ __forceinline__ float lo16(u32 u) { return __uint_as_float(u << 16); }
__device__ __forceinline__ float hi16(u32 u) { return __uint_as_float(u & 0xffff0000u); }
__device__ __forceinline__ u32 pack2(float a, float b) {
    return (u32)f2bf(a) | (((u32)f2bf(b)) << 16);
}
__device__ __forceinline__ float fast_tanh(float v) {
    return 1.f - 2.f / (__expf(2.f * v) + 1.f);
}

// ---------------- prep: transpose + 3 bpacks + zero cnt, one launch ----------------
__device__ __forceinline__ void bpack_body(const float* __restrict__ W, u16* __restrict__ out,
                                           int FIN, int NOUT, int idx) {
    int j = idx & 7;
    int lane = (idx >> 3) & 63;
    int rest = idx >> 9;
    int CT = NOUT >> 4;
    int ct = rest % CT;
    int ks = rest / CT;
    int k = ks * 32 + (lane >> 4) * 8 + j;
    int col = ct * 16 + (lane & 15);
    int wrow = (k % FIN) * 5 + (k / FIN);
    out[idx] = f2bf(W[wrow * NOUT + col]);
}

__global__ __launch_bounds__(256) void prep_kernel(
    const float2* __restrict__ y, u32* __restrict__ X0,
    const float* __restrict__ W_lat, u16* __restrict__ bpk1,
    const float* __restrict__ W_units, u16* __restrict__ bpk2,
    const float* __restrict__ W_final, u16* __restrict__ bpkP,
    int* __restrict__ cnt) {
    int b = blockIdx.x, t = threadIdx.x;
    if (b < 10000) {
        int idx = b * 256 + t;  // NB*32 = 2.56M exactly
        int fh = idx & 31;
        int rb = idx >> 5;
        int bb = rb & 7;
        int n = rb >> 3;
        float2 v = y[((size_t)bb * N_NODES + n) * 32 + fh];
        X0[idx] = pack2(v.x, v.y);
    } else if (b < 10080) {
        bpack_body(W_lat, bpk1, 64, 64, (b - 10000) * 256 + t);
    } else if (b < 10240) {
        bpack_body(W_units, bpk2, 64, 128, (b - 10080) * 256 + t);
    } else if (b < 10400) {
        // bpackP: K=128, NOUT=320; slot0 = W[:,0]-W[:,2]-W[:,4], slot m>=1 = W[:,m]
        int idx = (b - 10240) * 256 + t;  // < 40960
        int j8 = idx & 7;
        int lane = (idx >> 3) & 63;
        int rest = idx >> 9;
        int ct = rest % 20;
        int ks = rest / 20;
        int k = ks * 32 + (lane >> 4) * 8 + j8;
        int col = ct * 16 + (lane & 15);
        int slot = col >> 6, j = col & 63;
        float v;
        if (slot == 0)
            v = W_final[(k * 5 + 0) * 64 + j] - W_final[(k * 5 + 2) * 64 + j] -
                W_final[(k * 5 + 4) * 64 + j];
        else
            v = W_final[(k * 5 + slot) * 64 + j];
        bpkP[idx] = f2bf(v);
    } else {
        int idx = (b - 10400) * 256 + t;
        if (idx < 2 * N_NODES) cnt[idx] = 0;
    }
}

// ---------------- CSR build ----------------
__global__ void count_kernel(const int* __restrict__ rows, const int* __restrict__ cols,
                             int* __restrict__ cnt1, int* __restrict__ cnt2) {
    int e = blockIdx.x * 256 + threadIdx.x;
    if (e < NEDGE) {
        atomicAdd(&cnt1[cols[e]], 1);  // support1: dst = cols
        atomicAdd(&cnt2[rows[e]], 1);  // support2: dst = rows
    }
}

__global__ void blocksum_kernel(const int* __restrict__ cnt, int* __restrict__ bsums) {
    __shared__ int red[4];
    int arr = blockIdx.x / SCAN_CH;
    int c = blockIdx.x % SCAN_CH;
    int idx = c * 256 + threadIdx.x;
    int v = (idx < N_NODES) ? cnt[arr * N_NODES + idx] : 0;
#pragma unroll
    for (int off = 32; off; off >>= 1) v += __shfl_down(v, off, 64);
    int wv = threadIdx.x >> 6, ln = threadIdx.x & 63;
    if (ln == 0) red[wv] = v;
    __syncthreads();
    if (threadIdx.x == 0) bsums[blockIdx.x] = red[0] + red[1] + red[2] + red[3];
}

__global__ void scanmid_kernel(int* __restrict__ bsums, int* __restrict__ rowptr1,
                               int* __restrict__ rowptr2) {
    __shared__ int lds[128];
    int t = threadIdx.x;
    int seg = t >> 6, pos = t & 63;
    int v = (pos < SCAN_CH) ? bsums[seg * SCAN_CH + pos] : 0;
    lds[t] = v;
    __syncthreads();
    for (int off = 1; off < 64; off <<= 1) {
        int add = (pos >= off) ? lds[t - off] : 0;
        __syncthreads();
        lds[t] += add;
        __syncthreads();
    }
    if (pos < SCAN_CH) bsums[seg * SCAN_CH + pos] = pos ? lds[t - 1] : 0;
    if (t == 0) { rowptr1[N_NODES] = NEDGE; rowptr2[N_NODES] = NEDGE; }
}

__global__ void scanapply_kernel(int* __restrict__ cnt, const int* __restrict__ bsums,
                                 int* __restrict__ rowptr1, int* __restrict__ rowptr2) {
    __shared__ int lds[256];
    int arr = blockIdx.x / SCAN_CH;
    int c = blockIdx.x % SCAN_CH;
    int idx = c * 256 + threadIdx.x;
    bool ok = idx < N_NODES;
    int v = ok ? cnt[arr * N_NODES + idx] : 0;
    int t = threadIdx.x;
    lds[t] = v;
    __syncthreads();
    for (int off = 1; off < 256; off <<= 1) {
        int add = (t >= off) ? lds[t - off] : 0;
        __syncthreads();
        lds[t] += add;
        __syncthreads();
    }
    int excl = lds[t] - v + bsums[blockIdx.x];
    if (ok) {
        int* rp = arr ? rowptr2 : rowptr1;
        rp[idx] = excl;
        cnt[arr * N_NODES + idx] = excl;  // cursor
    }
}

__global__ void scatter_kernel(const int* __restrict__ rows, const int* __restrict__ cols,
                               const float* __restrict__ w1, const float* __restrict__ w2,
                               int* __restrict__ cur1, int* __restrict__ cur2,
                               int2* __restrict__ edges1, int2* __restrict__ edges2) {
    int e = blockIdx.x * 256 + threadIdx.x;
    if (e < NEDGE) {
        int r = rows[e], c = cols[e];
        int p1 = atomicAdd(&cur1[c], 1);
        edges1[p1] = make_int2(r, __float_as_int(w1[e]));
        int p2 = atomicAdd(&cur2[r], 1);
        edges2[p2] = make_int2(c, __float_as_int(w2[e]));
    }
}

// ---------------- SpMM: wave-per-node, dual-list (A-half / B-half) ----------------
// virtual node v<N: out=alpha*(S1@XinA)+beta*XprevA ; v>=N: same with list2/B ptrs.
// Row = 256 u32 (512 bf16); lane holds uint4 (8 bf16).
__device__ __forceinline__ void gather_row(const u32* __restrict__ Xin,
                                           const int* __restrict__ rp,
                                           const int2* __restrict__ eg,
                                           int n, int lane, float* acc) {
    int e0 = rp[n], e1 = rp[n + 1];
    for (int base = e0; base < e1; base += 64) {
        int m = min(64, e1 - base);
        int2 me = make_int2(0, 0);
        if (lane < m) me = eg[base + lane];
        for (int j = 0; j < m; j++) {
            int src = __shfl(me.x, j, 64);
            float w = __int_as_float(__shfl(me.y, j, 64));
            uint4 u = *(const uint4*)(Xin + (size_t)src * 256 + lane * 4);
            acc[0] += w * lo16(u.x); acc[1] += w * hi16(u.x);
            acc[2] += w * lo16(u.y); acc[3] += w * hi16(u.y);
            acc[4] += w * lo16(u.z); acc[5] += w * hi16(u.z);
            acc[6] += w * lo16(u.w); acc[7] += w * hi16(u.w);
        }
    }
}

__global__ __launch_bounds__(256) void spmm2_kernel(
    const u32* __restrict__ XinA, const u32* __restrict__ XprevA, u32* __restrict__ XoutA,
    const u32* __restrict__ XinB, const u32* __restrict__ XprevB, u32* __restrict__ XoutB,
    const int* __restrict__ rowptr1, const int2* __restrict__ edges1,
    const int* __restrict__ rowptr2, const int2* __restrict__ edges2,
    float alpha, float beta) {
    int lane = threadIdx.x & 63;
    int v = blockIdx.x * 4 + (threadIdx.x >> 6);
    if (v >= 2 * N_NODES) return;
    bool hB = v >= N_NODES;
    int n = hB ? v - N_NODES : v;
    const u32* Xin = hB ? XinB : XinA;
    const u32* Xprev = hB ? XprevB : XprevA;
    u32* Xout = hB ? XoutB : XoutA;
    const int* rp = hB ? rowptr2 : rowptr1;
    const int2* eg = hB ? edges2 : edges1;

    float acc[8] = {0.f, 0.f, 0.f, 0.f, 0.f, 0.f, 0.f, 0.f};
    gather_row(Xin, rp, eg, n, lane, acc);

    size_t o = (size_t)n * 256 + lane * 4;
    if (beta != 0.f) {
        uint4 p = *(const uint4*)(Xprev + o);
        acc[0] = alpha * acc[0] + beta * lo16(p.x); acc[1] = alpha * acc[1] + beta * hi16(p.x);
        acc[2] = alpha * acc[2] + beta * lo16(p.y); acc[3] = alpha * acc[3] + beta * hi16(p.y);
        acc[4] = alpha * acc[4] + beta * lo16(p.z); acc[5] = alpha * acc[5] + beta * hi16(p.z);
        acc[6] = alpha * acc[6] + beta * lo16(p.w); acc[7] = alpha * acc[7] + beta * hi16(p.w);
    } else {
#pragma unroll
        for (int i = 0; i < 8; i++) acc[i] *= alpha;
    }
    uint4 r;
    r.x = pack2(acc[0], acc[1]);
    r.y = pack2(acc[2], acc[3]);
    r.z = pack2(acc[4], acc[5]);
    r.w = pack2(acc[6], acc[7]);
    *(uint4*)(Xout + o) = r;
}

// final: out = -theta * tanh(Q + S1@T1 + S2@T2), fp32 (B,N,64) layout
__global__ __launch_bounds__(256) void spmm_final_kernel(
    const u32* __restrict__ T1, const u32* __restrict__ T2,
    const u32* __restrict__ Q, const u32* __restrict__ theta,
    const int* __restrict__ rowptr1, const int2* __restrict__ edges1,
    const int* __restrict__ rowptr2, const int2* __restrict__ edges2,
    float* __restrict__ outF) {
    int lane = threadIdx.x & 63;
    int n = blockIdx.x * 4 + (threadIdx.x >> 6);
    if (n >= N_NODES) return;

    float acc[8] = {0.f, 0.f, 0.f, 0.f, 0.f, 0.f, 0.f, 0.f};
    gather_row(T1, rowptr1, edges1, n, lane, acc);
    gather_row(T2, rowptr2, edges2, n, lane, acc);

    size_t o = (size_t)n * 256 + lane * 4;
    uint4 q = *(const uint4*)(Q + o);
    uint4 th = *(const uint4*)(theta + o);
    float res[8];
    res[0] = -lo16(th.x) * fast_tanh(lo16(q.x) + acc[0]);
    res[1] = -hi16(th.x) * fast_tanh(hi16(q.x) + acc[1]);
    res[2] = -lo16(th.y) * fast_tanh(lo16(q.y) + acc[2]);
    res[3] = -hi16(th.y) * fast_tanh(hi16(q.y) + acc[3]);
    res[4] = -lo16(th.z) * fast_tanh(lo16(q.z) + acc[4]);
    res[5] = -hi16(th.z) * fast_tanh(hi16(q.z) + acc[5]);
    res[6] = -lo16(th.w) * fast_tanh(lo16(q.w) + acc[6]);
    res[7] = -hi16(th.w) * fast_tanh(hi16(q.w) + acc[7]);
    int b = lane >> 3;
    int f0 = ((lane * 4) & 31) * 2;
    float* dst = outF + (size_t)b * (N_NODES * 64) + (size_t)n * 64 + f0;
    *(float4*)(dst) = make_float4(res[0], res[1], res[2], res[3]);
    *(float4*)(dst + 4) = make_float4(res[4], res[5], res[6], res[7]);
}

// ---------------- MFMA GEMM: C(80000 x NOUT) = A(80000 x NM*FIN) @ Bp ----------------
struct Slabs { const u16* p[5]; };

// ACT: 0 = plain (+bias on slot0) -> node-major 64-wide slabs; 1 = sigmoid; 2 = tanh
template <int FIN, int NM, int NOUT, int ACT>
__global__ __launch_bounds__(256) void gemm_kernel(
    Slabs A, const u16* __restrict__ Bp, const float* __restrict__ bias,
    u16* __restrict__ Cout) {
    constexpr int K = NM * FIN;
    constexpr int KS = K / 32;
    constexpr int CT = NOUT / 16;
    int lane = threadIdx.x & 63;
    int wave = threadIdx.x >> 6;
    int rowBase = blockIdx.x * 128 + wave * 32;
    int mrow = lane & 15;
    int kq = lane >> 4;

    float4v acc[2][CT];
#pragma unroll
    for (int s = 0; s < 2; s++)
#pragma unroll
        for (int c = 0; c < CT; c++) acc[s][c] = (float4v){0.f, 0.f, 0.f, 0.f};

    for (int ks = 0; ks < KS; ks++) {
        int k = ks * 32 + kq * 8;
        int m = k / FIN;  // uniform within ks
        int koff = k % FIN;
        const u16* abase = A.p[m] + (size_t)(rowBase + mrow) * FIN + koff;
        short8 a0 = *(const short8*)(abase);
        short8 a1 = *(const short8*)(abase + 16 * FIN);
        const u16* bbase = Bp + ((size_t)(ks * CT) * 64 + lane) * 8;
#pragma unroll
        for (int ct = 0; ct < CT; ct++) {
            short8 b = *(const short8*)(bbase + (size_t)ct * 64 * 8);
            acc[0][ct] = __builtin_amdgcn_mfma_f32_16x16x32_bf16(a0, b, acc[0][ct], 0, 0, 0);
            acc[1][ct] = __builtin_amdgcn_mfma_f32_16x16x32_bf16(a1, b, acc[1][ct], 0, 0, 0);
        }
    }

#pragma unroll
    for (int sub = 0; sub < 2; sub++) {
        int rowq = rowBase + sub * 16 + kq * 4;
#pragma unroll
        for (int ct = 0; ct < CT; ct++) {
            int col = ct * 16 + mrow;
            float bsv;
            if (ACT == 0) bsv = (col < 64) ? bias[col] : 0.f;
            else bsv = bias[col];
#pragma unroll
            for (int i = 0; i < 4; i++) {
                float v = acc[sub][ct][i] + bsv;
                int r = rowq + i;
                if (ACT == 0) {
                    Cout[(size_t)(col >> 6) * ((size_t)NB * 64) + (size_t)r * 64 + (col & 63)] = f2bf(v);
                } else if (ACT == 1) {
                    v = 1.f / (1.f + __expf(-v));
                    Cout[(size_t)r * NOUT + col] = f2bf(v);
                } else {
                    Cout[(size_t)r * NOUT + col] = f2bf(fast_tanh(v));
                }
            }
        }
    }
}

// ---------------- launch ----------------
extern "C" void kernel_launch(void* const* d_in, const int* in_sizes, int n_in,
                              void* d_out, int out_size, void* d_ws, size_t ws_size,
                              hipStream_t stream) {
    const float* y     = (const float*)d_in[0];
    const float* W_lat = (const float*)d_in[1];
    const float* b_lat = (const float*)d_in[2];
    const float* W_units = (const float*)d_in[3];
    const float* b_units = (const float*)d_in[4];
    const float* W_final = (const float*)d_in[5];
    const float* sup1w = (const float*)d_in[6];
    const float* sup2w = (const float*)d_in[7];
    const int* rows    = (const int*)d_in[8];
    const int* cols    = (const int*)d_in[9];
    float* out = (float*)d_out;

    char* ws = (char*)d_ws;
    size_t off = 0;
    auto alloc = [&](size_t bytes) -> void* {
        void* p = ws + off;
        off += (bytes + 511) & ~(size_t)511;
        return p;
    };
    int* rowptr1 = (int*)alloc((N_NODES + 1) * 4);
    int* rowptr2 = (int*)alloc((N_NODES + 1) * 4);
    int* cnt = (int*)alloc((size_t)2 * N_NODES * 4);
    int* cnt1 = cnt;
    int* cnt2 = cnt + N_NODES;
    int* bsums = (int*)alloc(2 * SCAN_CH * 4);
    int2* edges1 = (int2*)alloc((size_t)NEDGE * 8);
    int2* edges2 = (int2*)alloc((size_t)NEDGE * 8);
    u16* bpk1 = (u16*)alloc((size_t)320 * 64 * 2);
    u16* bpk2 = (u16*)alloc((size_t)320 * 128 * 2);
    u16* bpkP = (u16*)alloc((size_t)40960 * 2);
    u16* theta = (u16*)alloc((size_t)NB * 64 * 2);
    u16* S = (u16*)alloc((size_t)5 * NB * 64 * 2);  // X-series; later overlaid by Q/P slabs
    u16* H0 = (u16*)alloc((size_t)NB * 128 * 2);
    u16* T1 = (u16*)alloc((size_t)NB * 64 * 2);
    u16* T2 = (u16*)alloc((size_t)NB * 64 * 2);
    u16* P = S;  // Q/P slabs overlay S (S dead after gemm1/gemm2)

    const size_t SLAB = (size_t)NB * 64;

    prep_kernel<<<10479, 256, 0, stream>>>((const float2*)y, (u32*)S, W_lat, bpk1,
                                           W_units, bpk2, W_final, bpkP, cnt);
    count_kernel<<<(NEDGE + 255) / 256, 256, 0, stream>>>(rows, cols, cnt1, cnt2);
    blocksum_kernel<<<2 * SCAN_CH, 256, 0, stream>>>(cnt, bsums);
    scanmid_kernel<<<1, 128, 0, stream>>>(bsums, rowptr1, rowptr2);
    scanapply_kernel<<<2 * SCAN_CH, 256, 0, stream>>>(cnt, bsums, rowptr1, rowptr2);
    scatter_kernel<<<(NEDGE + 255) / 256, 256, 0, stream>>>(rows, cols, sup1w, sup2w,
                                                            cnt1, cnt2, edges1, edges2);

    // x-side diffusion: X1 = S1@X0, X3 = S2@X0 ; X2 = 2*S1@X1 - X0, X4 = 2*S2@X3 - X0
    const u32* S0 = (const u32*)S;
    u32* X1 = (u32*)(S + 1 * SLAB);
    u32* X2 = (u32*)(S + 2 * SLAB);
    u32* X3 = (u32*)(S + 3 * SLAB);
    u32* X4 = (u32*)(S + 4 * SLAB);
    spmm2_kernel<<<5000, 256, 0, stream>>>(S0, nullptr, X1, S0, nullptr, X3,
                                           rowptr1, edges1, rowptr2, edges2, 1.f, 0.f);
    spmm2_kernel<<<5000, 256, 0, stream>>>(X1, S0, X2, X3, S0, X4,
                                           rowptr1, edges1, rowptr2, edges2, 2.f, -1.f);

    Slabs SX;
    for (int m = 0; m < 5; m++) SX.p[m] = S + (size_t)m * SLAB;
    gemm_kernel<64, 5, 64, 1><<<625, 256, 0, stream>>>(SX, bpk1, b_lat, theta);
    gemm_kernel<64, 5, 128, 2><<<625, 256, 0, stream>>>(SX, bpk2, b_units, H0);

    // P-GEMM: [Q|P1|P2|P3|P4] = H0 @ bpkP (Q = P0-P2-P4 + b_lat), overlays S
    Slabs SH;
    SH.p[0] = H0;
    gemm_kernel<128, 1, 320, 0><<<625, 256, 0, stream>>>(SH, bpkP, b_lat, P);

    const u32* Q  = (const u32*)(P + 0 * SLAB);
    const u32* P1 = (const u32*)(P + 1 * SLAB);
    const u32* P2 = (const u32*)(P + 2 * SLAB);
    const u32* P3 = (const u32*)(P + 3 * SLAB);
    const u32* P4 = (const u32*)(P + 4 * SLAB);
    // T1 = P1 + 2*S1@P2 ; T2 = P3 + 2*S2@P4
    spmm2_kernel<<<5000, 256, 0, stream>>>(P2, (const u32*)P1, (u32*)T1,
                                           P4, (const u32*)P3, (u32*)T2,
                                           rowptr1, edges1, rowptr2, edges2, 2.f, 1.f);
    // out = -theta * tanh(Q + S1@T1 + S2@T2)
    spmm_final_kernel<<<2500, 256, 0, stream>>>((const u32*)T1, (const u32*)T2, Q,
                                                (const u32*)theta,
                                                rowptr1, edges1, rowptr2, edges2, out);
}

// Round 5
// 377.512 us; speedup vs baseline: 1.5004x; 1.0209x over previous
//
#include <hip/hip_runtime.h>

#define N_NODES 10000
#define NEDGE 160000
#define NB 80000  /* N_NODES*BATCH */
#define SCAN_CH 40 /* 256-wide chunks per array */

typedef unsigned int u32;
typedef unsigned short u16;
typedef __attribute__((ext_vector_type(8))) short short8;
typedef __attribute__((ext_vector_type(4))) float float4v;

__device__ __forceinline__ float bf2f(u16 h) { return __uint_as_float(((u32)h) << 16); }
__device__ __forceinline__ u16 f2bf(float f) {
    u32 u = __float_as_uint(f);
    return (u16)((u + 0x7fffu + ((u >> 16) & 1u)) >> 16);
}
__device__ __forceinline__ float lo16(u32 u) { return __uint_as_float(u << 16); }
__device__ __forceinline__ float hi16(u32 u) { return __uint_as_float(u & 0xffff0000u); }
__device__ __forceinline__ u32 pack2(float a, float b) {
    return (u32)f2bf(a) | (((u32)f2bf(b)) << 16);
}
__device__ __forceinline__ float fast_tanh(float v) {
    return 1.f - 2.f / (__expf(2.f * v) + 1.f);
}

// ---------------- prep: transpose + fused bpack12 + bpackP + zero cnt ----------------
__global__ __launch_bounds__(256) void prep_kernel(
    const float2* __restrict__ y, u32* __restrict__ X0,
    const float* __restrict__ W_lat, const float* __restrict__ W_units,
    u16* __restrict__ bpk12,
    const float* __restrict__ W_final, u16* __restrict__ bpkP,
    int* __restrict__ cnt) {
    int b = blockIdx.x, t = threadIdx.x;
    if (b < 10000) {
        int idx = b * 256 + t;  // NB*32 = 2.56M exactly
        int fh = idx & 31;
        int rb = idx >> 5;
        int bb = rb & 7;
        int n = rb >> 3;
        float2 v = y[((size_t)bb * N_NODES + n) * 32 + fh];
        X0[idx] = pack2(v.x, v.y);
    } else if (b < 10240) {
        // fused bpack: K=320 (k = m*64+f, wrow = f*5+m), NOUT=192 (0..63 lat, 64..191 units)
        int idx = (b - 10000) * 256 + t;  // < 61440
        int j = idx & 7;
        int lane = (idx >> 3) & 63;
        int rest = idx >> 9;
        int ct = rest % 12;
        int ks = rest / 12;
        int k = ks * 32 + (lane >> 4) * 8 + j;
        int col = ct * 16 + (lane & 15);
        int wrow = (k % 64) * 5 + (k / 64);
        float v = (col < 64) ? W_lat[wrow * 64 + col] : W_units[wrow * 128 + (col - 64)];
        bpk12[idx] = f2bf(v);
    } else if (b < 10400) {
        // bpackP: K=128, NOUT=320; slot0 = W[:,0]-W[:,2]-W[:,4], slot m>=1 = W[:,m]
        int idx = (b - 10240) * 256 + t;  // < 40960
        int j8 = idx & 7;
        int lane = (idx >> 3) & 63;
        int rest = idx >> 9;
        int ct = rest % 20;
        int ks = rest / 20;
        int k = ks * 32 + (lane >> 4) * 8 + j8;
        int col = ct * 16 + (lane & 15);
        int slot = col >> 6, j = col & 63;
        float v;
        if (slot == 0)
            v = W_final[(k * 5 + 0) * 64 + j] - W_final[(k * 5 + 2) * 64 + j] -
                W_final[(k * 5 + 4) * 64 + j];
        else
            v = W_final[(k * 5 + slot) * 64 + j];
        bpkP[idx] = f2bf(v);
    } else {
        int idx = (b - 10400) * 256 + t;
        if (idx < 2 * N_NODES) cnt[idx] = 0;
    }
}

// ---------------- CSR build ----------------
__global__ void count_kernel(const int* __restrict__ rows, const int* __restrict__ cols,
                             int* __restrict__ cnt1, int* __restrict__ cnt2) {
    int e = blockIdx.x * 256 + threadIdx.x;
    if (e < NEDGE) {
        atomicAdd(&cnt1[cols[e]], 1);  // support1: dst = cols
        atomicAdd(&cnt2[rows[e]], 1);  // support2: dst = rows
    }
}

__global__ void blocksum_kernel(const int* __restrict__ cnt, int* __restrict__ bsums) {
    __shared__ int red[4];
    int arr = blockIdx.x / SCAN_CH;
    int c = blockIdx.x % SCAN_CH;
    int idx = c * 256 + threadIdx.x;
    int v = (idx < N_NODES) ? cnt[arr * N_NODES + idx] : 0;
#pragma unroll
    for (int off = 32; off; off >>= 1) v += __shfl_down(v, off, 64);
    int wv = threadIdx.x >> 6, ln = threadIdx.x & 63;
    if (ln == 0) red[wv] = v;
    __syncthreads();
    if (threadIdx.x == 0) bsums[blockIdx.x] = red[0] + red[1] + red[2] + red[3];
}

__global__ void scanmid_kernel(int* __restrict__ bsums, int* __restrict__ rowptr1,
                               int* __restrict__ rowptr2) {
    __shared__ int lds[128];
    int t = threadIdx.x;
    int seg = t >> 6, pos = t & 63;
    int v = (pos < SCAN_CH) ? bsums[seg * SCAN_CH + pos] : 0;
    lds[t] = v;
    __syncthreads();
    for (int off = 1; off < 64; off <<= 1) {
        int add = (pos >= off) ? lds[t - off] : 0;
        __syncthreads();
        lds[t] += add;
        __syncthreads();
    }
    if (pos < SCAN_CH) bsums[seg * SCAN_CH + pos] = pos ? lds[t - 1] : 0;
    if (t == 0) { rowptr1[N_NODES] = NEDGE; rowptr2[N_NODES] = NEDGE; }
}

__global__ void scanapply_kernel(int* __restrict__ cnt, const int* __restrict__ bsums,
                                 int* __restrict__ rowptr1, int* __restrict__ rowptr2) {
    __shared__ int lds[256];
    int arr = blockIdx.x / SCAN_CH;
    int c = blockIdx.x % SCAN_CH;
    int idx = c * 256 + threadIdx.x;
    bool ok = idx < N_NODES;
    int v = ok ? cnt[arr * N_NODES + idx] : 0;
    int t = threadIdx.x;
    lds[t] = v;
    __syncthreads();
    for (int off = 1; off < 256; off <<= 1) {
        int add = (t >= off) ? lds[t - off] : 0;
        __syncthreads();
        lds[t] += add;
        __syncthreads();
    }
    int excl = lds[t] - v + bsums[blockIdx.x];
    if (ok) {
        int* rp = arr ? rowptr2 : rowptr1;
        rp[idx] = excl;
        cnt[arr * N_NODES + idx] = excl;  // cursor
    }
}

__global__ void scatter_kernel(const int* __restrict__ rows, const int* __restrict__ cols,
                               const float* __restrict__ w1, const float* __restrict__ w2,
                               int* __restrict__ cur1, int* __restrict__ cur2,
                               int2* __restrict__ edges1, int2* __restrict__ edges2) {
    int e = blockIdx.x * 256 + threadIdx.x;
    if (e < NEDGE) {
        int r = rows[e], c = cols[e];
        int p1 = atomicAdd(&cur1[c], 1);
        edges1[p1] = make_int2(r, __float_as_int(w1[e]));
        int p2 = atomicAdd(&cur2[r], 1);
        edges2[p2] = make_int2(c, __float_as_int(w2[e]));
    }
}

// ---------------- SpMM: wave-per-node, dual-list (A-half / B-half) ----------------
__device__ __forceinline__ void gather_row(const u32* __restrict__ Xin,
                                           const int* __restrict__ rp,
                                           const int2* __restrict__ eg,
                                           int n, int lane, float* acc) {
    int e0 = rp[n], e1 = rp[n + 1];
    for (int base = e0; base < e1; base += 64) {
        int m = min(64, e1 - base);
        int2 me = make_int2(0, 0);
        if (lane < m) me = eg[base + lane];
        for (int j = 0; j < m; j++) {
            int src = __shfl(me.x, j, 64);
            float w = __int_as_float(__shfl(me.y, j, 64));
            uint4 u = *(const uint4*)(Xin + (size_t)src * 256 + lane * 4);
            acc[0] += w * lo16(u.x); acc[1] += w * hi16(u.x);
            acc[2] += w * lo16(u.y); acc[3] += w * hi16(u.y);
            acc[4] += w * lo16(u.z); acc[5] += w * hi16(u.z);
            acc[6] += w * lo16(u.w); acc[7] += w * hi16(u.w);
        }
    }
}

__global__ __launch_bounds__(256) void spmm2_kernel(
    const u32* __restrict__ XinA, const u32* __restrict__ XprevA, u32* __restrict__ XoutA,
    const u32* __restrict__ XinB, const u32* __restrict__ XprevB, u32* __restrict__ XoutB,
    const int* __restrict__ rowptr1, const int2* __restrict__ edges1,
    const int* __restrict__ rowptr2, const int2* __restrict__ edges2,
    float alpha, float beta) {
    int lane = threadIdx.x & 63;
    int v = blockIdx.x * 4 + (threadIdx.x >> 6);
    if (v >= 2 * N_NODES) return;
    bool hB = v >= N_NODES;
    int n = hB ? v - N_NODES : v;
    const u32* Xin = hB ? XinB : XinA;
    const u32* Xprev = hB ? XprevB : XprevA;
    u32* Xout = hB ? XoutB : XoutA;
    const int* rp = hB ? rowptr2 : rowptr1;
    const int2* eg = hB ? edges2 : edges1;

    float acc[8] = {0.f, 0.f, 0.f, 0.f, 0.f, 0.f, 0.f, 0.f};
    gather_row(Xin, rp, eg, n, lane, acc);

    size_t o = (size_t)n * 256 + lane * 4;
    if (beta != 0.f) {
        uint4 p = *(const uint4*)(Xprev + o);
        acc[0] = alpha * acc[0] + beta * lo16(p.x); acc[1] = alpha * acc[1] + beta * hi16(p.x);
        acc[2] = alpha * acc[2] + beta * lo16(p.y); acc[3] = alpha * acc[3] + beta * hi16(p.y);
        acc[4] = alpha * acc[4] + beta * lo16(p.z); acc[5] = alpha * acc[5] + beta * hi16(p.z);
        acc[6] = alpha * acc[6] + beta * lo16(p.w); acc[7] = alpha * acc[7] + beta * hi16(p.w);
    } else {
#pragma unroll
        for (int i = 0; i < 8; i++) acc[i] *= alpha;
    }
    uint4 r;
    r.x = pack2(acc[0], acc[1]);
    r.y = pack2(acc[2], acc[3]);
    r.z = pack2(acc[4], acc[5]);
    r.w = pack2(acc[6], acc[7]);
    *(uint4*)(Xout + o) = r;
}

// final: out = -theta * tanh(Q + S1@T1 + S2@T2), fp32 (B,N,64) layout
__global__ __launch_bounds__(256) void spmm_final_kernel(
    const u32* __restrict__ T1, const u32* __restrict__ T2,
    const u32* __restrict__ Q, const u32* __restrict__ theta,
    const int* __restrict__ rowptr1, const int2* __restrict__ edges1,
    const int* __restrict__ rowptr2, const int2* __restrict__ edges2,
    float* __restrict__ outF) {
    int lane = threadIdx.x & 63;
    int n = blockIdx.x * 4 + (threadIdx.x >> 6);
    if (n >= N_NODES) return;

    float acc[8] = {0.f, 0.f, 0.f, 0.f, 0.f, 0.f, 0.f, 0.f};
    gather_row(T1, rowptr1, edges1, n, lane, acc);
    gather_row(T2, rowptr2, edges2, n, lane, acc);

    size_t o = (size_t)n * 256 + lane * 4;
    uint4 q = *(const uint4*)(Q + o);
    uint4 th = *(const uint4*)(theta + o);
    float res[8];
    res[0] = -lo16(th.x) * fast_tanh(lo16(q.x) + acc[0]);
    res[1] = -hi16(th.x) * fast_tanh(hi16(q.x) + acc[1]);
    res[2] = -lo16(th.y) * fast_tanh(lo16(q.y) + acc[2]);
    res[3] = -hi16(th.y) * fast_tanh(hi16(q.y) + acc[3]);
    res[4] = -lo16(th.z) * fast_tanh(lo16(q.z) + acc[4]);
    res[5] = -hi16(th.z) * fast_tanh(hi16(q.z) + acc[5]);
    res[6] = -lo16(th.w) * fast_tanh(lo16(q.w) + acc[6]);
    res[7] = -hi16(th.w) * fast_tanh(hi16(q.w) + acc[7]);
    int b = lane >> 3;
    int f0 = ((lane * 4) & 31) * 2;
    float* dst = outF + (size_t)b * (N_NODES * 64) + (size_t)n * 64 + f0;
    *(float4*)(dst) = make_float4(res[0], res[1], res[2], res[3]);
    *(float4*)(dst + 4) = make_float4(res[4], res[5], res[6], res[7]);
}

// ---------------- MFMA GEMM with full A-prefetch ----------------
struct Slabs { const u16* p[5]; };

// MODE 0: plain (+bias1 on cols<64) -> 64-wide slabs at O1 (gemmP)
// MODE 1: fused: col<64 sigmoid(+bias1)->O1 (64-wide); col>=64 tanh(+bias2)->O2 (128-wide)
template <int FIN, int NM, int NOUT, int MODE>
__global__ __launch_bounds__(256) void gemm_kernel(
    Slabs A, const u16* __restrict__ Bp, const float* __restrict__ bias1,
    const float* __restrict__ bias2, u16* __restrict__ O1, u16* __restrict__ O2) {
    constexpr int K = NM * FIN;
    constexpr int KS = K / 32;
    constexpr int CT = NOUT / 16;
    int lane = threadIdx.x & 63;
    int wave = threadIdx.x >> 6;
    int rowBase = blockIdx.x * 128 + wave * 32;
    int mrow = lane & 15;
    int kq = lane >> 4;

    // hoist ALL A loads: KS*2 dwordx4 in flight, one latency instead of KS
    short8 a0[KS], a1[KS];
#pragma unroll
    for (int ks = 0; ks < KS; ks++) {
        int k = ks * 32 + kq * 8;
        int m = k / FIN;  // uniform within ks
        int koff = k % FIN;
        const u16* abase = A.p[m] + (size_t)(rowBase + mrow) * FIN + koff;
        a0[ks] = *(const short8*)(abase);
        a1[ks] = *(const short8*)(abase + 16 * FIN);
    }

    float4v acc[2][CT];
#pragma unroll
    for (int s = 0; s < 2; s++)
#pragma unroll
        for (int c = 0; c < CT; c++) acc[s][c] = (float4v){0.f, 0.f, 0.f, 0.f};

#pragma unroll
    for (int ks = 0; ks < KS; ks++) {
        const u16* bbase = Bp + ((size_t)(ks * CT) * 64 + lane) * 8;
#pragma unroll
        for (int ct = 0; ct < CT; ct++) {
            short8 b = *(const short8*)(bbase + (size_t)ct * 64 * 8);
            acc[0][ct] = __builtin_amdgcn_mfma_f32_16x16x32_bf16(a0[ks], b, acc[0][ct], 0, 0, 0);
            acc[1][ct] = __builtin_amdgcn_mfma_f32_16x16x32_bf16(a1[ks], b, acc[1][ct], 0, 0, 0);
        }
    }

#pragma unroll
    for (int sub = 0; sub < 2; sub++) {
        int rowq = rowBase + sub * 16 + kq * 4;
#pragma unroll
        for (int ct = 0; ct < CT; ct++) {
            int col = ct * 16 + mrow;
            float bsv;
            if (MODE == 0) bsv = (col < 64) ? bias1[col] : 0.f;
            else bsv = (col < 64) ? bias1[col] : bias2[col - 64];
#pragma unroll
            for (int i = 0; i < 4; i++) {
                float v = acc[sub][ct][i] + bsv;
                int r = rowq + i;
                if (MODE == 0) {
                    O1[(size_t)(col >> 6) * ((size_t)NB * 64) + (size_t)r * 64 + (col & 63)] = f2bf(v);
                } else {
                    if (col < 64) {
                        v = 1.f / (1.f + __expf(-v));
                        O1[(size_t)r * 64 + col] = f2bf(v);
                    } else {
                        O2[(size_t)r * 128 + (col - 64)] = f2bf(fast_tanh(v));
                    }
                }
            }
        }
    }
}

// ---------------- launch ----------------
extern "C" void kernel_launch(void* const* d_in, const int* in_sizes, int n_in,
                              void* d_out, int out_size, void* d_ws, size_t ws_size,
                              hipStream_t stream) {
    const float* y     = (const float*)d_in[0];
    const float* W_lat = (const float*)d_in[1];
    const float* b_lat = (const float*)d_in[2];
    const float* W_units = (const float*)d_in[3];
    const float* b_units = (const float*)d_in[4];
    const float* W_final = (const float*)d_in[5];
    const float* sup1w = (const float*)d_in[6];
    const float* sup2w = (const float*)d_in[7];
    const int* rows    = (const int*)d_in[8];
    const int* cols    = (const int*)d_in[9];
    float* out = (float*)d_out;

    char* ws = (char*)d_ws;
    size_t off = 0;
    auto alloc = [&](size_t bytes) -> void* {
        void* p = ws + off;
        off += (bytes + 511) & ~(size_t)511;
        return p;
    };
    int* rowptr1 = (int*)alloc((N_NODES + 1) * 4);
    int* rowptr2 = (int*)alloc((N_NODES + 1) * 4);
    int* cnt = (int*)alloc((size_t)2 * N_NODES * 4);
    int* cnt1 = cnt;
    int* cnt2 = cnt + N_NODES;
    int* bsums = (int*)alloc(2 * SCAN_CH * 4);
    int2* edges1 = (int2*)alloc((size_t)NEDGE * 8);
    int2* edges2 = (int2*)alloc((size_t)NEDGE * 8);
    u16* bpk12 = (u16*)alloc((size_t)61440 * 2);
    u16* bpkP = (u16*)alloc((size_t)40960 * 2);
    u16* theta = (u16*)alloc((size_t)NB * 64 * 2);
    u16* S = (u16*)alloc((size_t)5 * NB * 64 * 2);  // X-series; later overlaid by Q/P slabs
    u16* H0 = (u16*)alloc((size_t)NB * 128 * 2);
    u16* T1 = (u16*)alloc((size_t)NB * 64 * 2);
    u16* T2 = (u16*)alloc((size_t)NB * 64 * 2);
    u16* P = S;  // Q/P slabs overlay S (S dead after gemm12)

    const size_t SLAB = (size_t)NB * 64;

    prep_kernel<<<10479, 256, 0, stream>>>((const float2*)y, (u32*)S, W_lat, W_units,
                                           bpk12, W_final, bpkP, cnt);
    count_kernel<<<(NEDGE + 255) / 256, 256, 0, stream>>>(rows, cols, cnt1, cnt2);
    blocksum_kernel<<<2 * SCAN_CH, 256, 0, stream>>>(cnt, bsums);
    scanmid_kernel<<<1, 128, 0, stream>>>(bsums, rowptr1, rowptr2);
    scanapply_kernel<<<2 * SCAN_CH, 256, 0, stream>>>(cnt, bsums, rowptr1, rowptr2);
    scatter_kernel<<<(NEDGE + 255) / 256, 256, 0, stream>>>(rows, cols, sup1w, sup2w,
                                                            cnt1, cnt2, edges1, edges2);

    // x-side diffusion: X1 = S1@X0, X3 = S2@X0 ; X2 = 2*S1@X1 - X0, X4 = 2*S2@X3 - X0
    const u32* S0 = (const u32*)S;
    u32* X1 = (u32*)(S + 1 * SLAB);
    u32* X2 = (u32*)(S + 2 * SLAB);
    u32* X3 = (u32*)(S + 3 * SLAB);
    u32* X4 = (u32*)(S + 4 * SLAB);
    spmm2_kernel<<<5000, 256, 0, stream>>>(S0, nullptr, X1, S0, nullptr, X3,
                                           rowptr1, edges1, rowptr2, edges2, 1.f, 0.f);
    spmm2_kernel<<<5000, 256, 0, stream>>>(X1, S0, X2, X3, S0, X4,
                                           rowptr1, edges1, rowptr2, edges2, 2.f, -1.f);

    Slabs SX;
    for (int m = 0; m < 5; m++) SX.p[m] = S + (size_t)m * SLAB;
    // fused: theta = sigmoid(X@W_lat + b_lat), H0 = tanh(X@W_units + b_units)
    gemm_kernel<64, 5, 192, 1><<<625, 256, 0, stream>>>(SX, bpk12, b_lat, b_units, theta, H0);

    // P-GEMM: [Q|P1|P2|P3|P4] = H0 @ bpkP (Q = P0-P2-P4 + b_lat), overlays S
    Slabs SH;
    SH.p[0] = H0;
    gemm_kernel<128, 1, 320, 0><<<625, 256, 0, stream>>>(SH, bpkP, b_lat, nullptr, P, nullptr);

    const u32* Q  = (const u32*)(P + 0 * SLAB);
    const u32* P1 = (const u32*)(P + 1 * SLAB);
    const u32* P2 = (const u32*)(P + 2 * SLAB);
    const u32* P3 = (const u32*)(P + 3 * SLAB);
    const u32* P4 = (const u32*)(P + 4 * SLAB);
    // T1 = P1 + 2*S1@P2 ; T2 = P3 + 2*S2@P4
    spmm2_kernel<<<5000, 256, 0, stream>>>(P2, (const u32*)P1, (u32*)T1,
                                           P4, (const u32*)P3, (u32*)T2,
                                           rowptr1, edges1, rowptr2, edges2, 2.f, 1.f);
    // out = -theta * tanh(Q + S1@T1 + S2@T2)
    spmm_final_kernel<<<2500, 256, 0, stream>>>((const u32*)T1, (const u32*)T2, Q,
                                                (const u32*)theta,
                                                rowptr1, edges1, rowptr2, edges2, out);
}

// Round 6
// 348.012 us; speedup vs baseline: 1.6276x; 1.0848x over previous
//
#include <hip/hip_runtime.h>

#define N_NODES 10000
#define NEDGE 160000
#define NB 80000  /* N_NODES*BATCH */
#define SCAN_CH 40 /* 256-wide chunks per array */

typedef unsigned int u32;
typedef unsigned short u16;
typedef __attribute__((ext_vector_type(8))) short short8;
typedef __attribute__((ext_vector_type(4))) float float4v;

__device__ __forceinline__ float bf2f(u16 h) { return __uint_as_float(((u32)h) << 16); }
__device__ __forceinline__ u16 f2bf(float f) {
    u32 u = __float_as_uint(f);
    return (u16)((u + 0x7fffu + ((u >> 16) & 1u)) >> 16);
}
__device__ __forceinline__ float lo16(u32 u) { return __uint_as_float(u << 16); }
__device__ __forceinline__ float hi16(u32 u) { return __uint_as_float(u & 0xffff0000u); }
__device__ __forceinline__ u32 pack2(float a, float b) {
    return (u32)f2bf(a) | (((u32)f2bf(b)) << 16);
}
__device__ __forceinline__ float fast_tanh(float v) {
    return 1.f - 2.f / (__expf(2.f * v) + 1.f);
}

// ---------------- prep: transpose + fused bpack12 + bpackP + zero cnt ----------------
__global__ __launch_bounds__(256) void prep_kernel(
    const float2* __restrict__ y, u32* __restrict__ X0,
    const float* __restrict__ W_lat, const float* __restrict__ W_units,
    u16* __restrict__ bpk12,
    const float* __restrict__ W_final, u16* __restrict__ bpkP,
    int* __restrict__ cnt) {
    int b = blockIdx.x, t = threadIdx.x;
    if (b < 10000) {
        int idx = b * 256 + t;  // NB*32 = 2.56M exactly
        int fh = idx & 31;
        int rb = idx >> 5;
        int bb = rb & 7;
        int n = rb >> 3;
        float2 v = y[((size_t)bb * N_NODES + n) * 32 + fh];
        X0[idx] = pack2(v.x, v.y);
    } else if (b < 10240) {
        // fused bpack: K=320 (k = m*64+f, wrow = f*5+m), NOUT=192 (0..63 lat, 64..191 units)
        int idx = (b - 10000) * 256 + t;  // < 61440
        int j = idx & 7;
        int lane = (idx >> 3) & 63;
        int rest = idx >> 9;
        int ct = rest % 12;
        int ks = rest / 12;
        int k = ks * 32 + (lane >> 4) * 8 + j;
        int col = ct * 16 + (lane & 15);
        int wrow = (k % 64) * 5 + (k / 64);
        float v = (col < 64) ? W_lat[wrow * 64 + col] : W_units[wrow * 128 + (col - 64)];
        bpk12[idx] = f2bf(v);
    } else if (b < 10400) {
        // bpackP: K=128, NOUT=320; slot0 = W[:,0]-W[:,2]-W[:,4], slot m>=1 = W[:,m]
        int idx = (b - 10240) * 256 + t;  // < 40960
        int j8 = idx & 7;
        int lane = (idx >> 3) & 63;
        int rest = idx >> 9;
        int ct = rest % 20;
        int ks = rest / 20;
        int k = ks * 32 + (lane >> 4) * 8 + j8;
        int col = ct * 16 + (lane & 15);
        int slot = col >> 6, j = col & 63;
        float v;
        if (slot == 0)
            v = W_final[(k * 5 + 0) * 64 + j] - W_final[(k * 5 + 2) * 64 + j] -
                W_final[(k * 5 + 4) * 64 + j];
        else
            v = W_final[(k * 5 + slot) * 64 + j];
        bpkP[idx] = f2bf(v);
    } else {
        int idx = (b - 10400) * 256 + t;
        if (idx < 2 * N_NODES) cnt[idx] = 0;
    }
}

// ---------------- CSR build ----------------
__global__ void count_kernel(const int* __restrict__ rows, const int* __restrict__ cols,
                             int* __restrict__ cnt1, int* __restrict__ cnt2) {
    int e = blockIdx.x * 256 + threadIdx.x;
    if (e < NEDGE) {
        atomicAdd(&cnt1[cols[e]], 1);  // support1: dst = cols
        atomicAdd(&cnt2[rows[e]], 1);  // support2: dst = rows
    }
}

__global__ void blocksum_kernel(const int* __restrict__ cnt, int* __restrict__ bsums) {
    __shared__ int red[4];
    int arr = blockIdx.x / SCAN_CH;
    int c = blockIdx.x % SCAN_CH;
    int idx = c * 256 + threadIdx.x;
    int v = (idx < N_NODES) ? cnt[arr * N_NODES + idx] : 0;
#pragma unroll
    for (int off = 32; off; off >>= 1) v += __shfl_down(v, off, 64);
    int wv = threadIdx.x >> 6, ln = threadIdx.x & 63;
    if (ln == 0) red[wv] = v;
    __syncthreads();
    if (threadIdx.x == 0) bsums[blockIdx.x] = red[0] + red[1] + red[2] + red[3];
}

__global__ void scanmid_kernel(int* __restrict__ bsums, int* __restrict__ rowptr1,
                               int* __restrict__ rowptr2) {
    __shared__ int lds[128];
    int t = threadIdx.x;
    int seg = t >> 6, pos = t & 63;
    int v = (pos < SCAN_CH) ? bsums[seg * SCAN_CH + pos] : 0;
    lds[t] = v;
    __syncthreads();
    for (int off = 1; off < 64; off <<= 1) {
        int add = (pos >= off) ? lds[t - off] : 0;
        __syncthreads();
        lds[t] += add;
        __syncthreads();
    }
    if (pos < SCAN_CH) bsums[seg * SCAN_CH + pos] = pos ? lds[t - 1] : 0;
    if (t == 0) { rowptr1[N_NODES] = NEDGE; rowptr2[N_NODES] = NEDGE; }
}

__global__ void scanapply_kernel(int* __restrict__ cnt, const int* __restrict__ bsums,
                                 int* __restrict__ rowptr1, int* __restrict__ rowptr2) {
    __shared__ int lds[256];
    int arr = blockIdx.x / SCAN_CH;
    int c = blockIdx.x % SCAN_CH;
    int idx = c * 256 + threadIdx.x;
    bool ok = idx < N_NODES;
    int v = ok ? cnt[arr * N_NODES + idx] : 0;
    int t = threadIdx.x;
    lds[t] = v;
    __syncthreads();
    for (int off = 1; off < 256; off <<= 1) {
        int add = (t >= off) ? lds[t - off] : 0;
        __syncthreads();
        lds[t] += add;
        __syncthreads();
    }
    int excl = lds[t] - v + bsums[blockIdx.x];
    if (ok) {
        int* rp = arr ? rowptr2 : rowptr1;
        rp[idx] = excl;
        cnt[arr * N_NODES + idx] = excl;  // cursor
    }
}

__global__ void scatter_kernel(const int* __restrict__ rows, const int* __restrict__ cols,
                               const float* __restrict__ w1, const float* __restrict__ w2,
                               int* __restrict__ cur1, int* __restrict__ cur2,
                               int2* __restrict__ edges1, int2* __restrict__ edges2) {
    int e = blockIdx.x * 256 + threadIdx.x;
    if (e < NEDGE) {
        int r = rows[e], c = cols[e];
        int p1 = atomicAdd(&cur1[c], 1);
        edges1[p1] = make_int2(r, __float_as_int(w1[e]));
        int p2 = atomicAdd(&cur2[r], 1);
        edges2[p2] = make_int2(c, __float_as_int(w2[e]));
    }
}

// ---------------- SpMM gather: 4-deep MLP unroll ----------------
__device__ __forceinline__ void gacc(float* acc, float w, uint4 u) {
    acc[0] += w * lo16(u.x); acc[1] += w * hi16(u.x);
    acc[2] += w * lo16(u.y); acc[3] += w * hi16(u.y);
    acc[4] += w * lo16(u.z); acc[5] += w * hi16(u.z);
    acc[6] += w * lo16(u.w); acc[7] += w * hi16(u.w);
}

__device__ __forceinline__ void gather_row(const u32* __restrict__ Xin,
                                           const int* __restrict__ rp,
                                           const int2* __restrict__ eg,
                                           int n, int lane, float* acc) {
    int e0 = rp[n], e1 = rp[n + 1];
    for (int base = e0; base < e1; base += 64) {
        int m = min(64, e1 - base);
        int2 me = make_int2(0, 0);
        if (lane < m) me = eg[base + lane];
        int j = 0;
        for (; j + 4 <= m; j += 4) {
            int s0 = __shfl(me.x, j, 64);
            int s1 = __shfl(me.x, j + 1, 64);
            int s2 = __shfl(me.x, j + 2, 64);
            int s3 = __shfl(me.x, j + 3, 64);
            float w0 = __int_as_float(__shfl(me.y, j, 64));
            float w1 = __int_as_float(__shfl(me.y, j + 1, 64));
            float w2 = __int_as_float(__shfl(me.y, j + 2, 64));
            float w3 = __int_as_float(__shfl(me.y, j + 3, 64));
            uint4 u0 = *(const uint4*)(Xin + (size_t)s0 * 256 + lane * 4);
            uint4 u1 = *(const uint4*)(Xin + (size_t)s1 * 256 + lane * 4);
            uint4 u2 = *(const uint4*)(Xin + (size_t)s2 * 256 + lane * 4);
            uint4 u3 = *(const uint4*)(Xin + (size_t)s3 * 256 + lane * 4);
            gacc(acc, w0, u0);
            gacc(acc, w1, u1);
            gacc(acc, w2, u2);
            gacc(acc, w3, u3);
        }
        for (; j < m; j++) {
            int src = __shfl(me.x, j, 64);
            float w = __int_as_float(__shfl(me.y, j, 64));
            uint4 u = *(const uint4*)(Xin + (size_t)src * 256 + lane * 4);
            gacc(acc, w, u);
        }
    }
}

__global__ __launch_bounds__(256) void spmm2_kernel(
    const u32* __restrict__ XinA, const u32* __restrict__ XprevA, u32* __restrict__ XoutA,
    const u32* __restrict__ XinB, const u32* __restrict__ XprevB, u32* __restrict__ XoutB,
    const int* __restrict__ rowptr1, const int2* __restrict__ edges1,
    const int* __restrict__ rowptr2, const int2* __restrict__ edges2,
    float alpha, float beta) {
    int lane = threadIdx.x & 63;
    int v = blockIdx.x * 4 + (threadIdx.x >> 6);
    if (v >= 2 * N_NODES) return;
    bool hB = v >= N_NODES;
    int n = hB ? v - N_NODES : v;
    const u32* Xin = hB ? XinB : XinA;
    const u32* Xprev = hB ? XprevB : XprevA;
    u32* Xout = hB ? XoutB : XoutA;
    const int* rp = hB ? rowptr2 : rowptr1;
    const int2* eg = hB ? edges2 : edges1;

    float acc[8] = {0.f, 0.f, 0.f, 0.f, 0.f, 0.f, 0.f, 0.f};
    gather_row(Xin, rp, eg, n, lane, acc);

    size_t o = (size_t)n * 256 + lane * 4;
    if (beta != 0.f) {
        uint4 p = *(const uint4*)(Xprev + o);
        acc[0] = alpha * acc[0] + beta * lo16(p.x); acc[1] = alpha * acc[1] + beta * hi16(p.x);
        acc[2] = alpha * acc[2] + beta * lo16(p.y); acc[3] = alpha * acc[3] + beta * hi16(p.y);
        acc[4] = alpha * acc[4] + beta * lo16(p.z); acc[5] = alpha * acc[5] + beta * hi16(p.z);
        acc[6] = alpha * acc[6] + beta * lo16(p.w); acc[7] = alpha * acc[7] + beta * hi16(p.w);
    } else {
#pragma unroll
        for (int i = 0; i < 8; i++) acc[i] *= alpha;
    }
    uint4 r;
    r.x = pack2(acc[0], acc[1]);
    r.y = pack2(acc[2], acc[3]);
    r.z = pack2(acc[4], acc[5]);
    r.w = pack2(acc[6], acc[7]);
    *(uint4*)(Xout + o) = r;
}

// final: out = -theta * tanh(Q + S1@T1 + S2@T2), fp32 (B,N,64) layout
__global__ __launch_bounds__(256) void spmm_final_kernel(
    const u32* __restrict__ T1, const u32* __restrict__ T2,
    const u32* __restrict__ Q, const u32* __restrict__ theta,
    const int* __restrict__ rowptr1, const int2* __restrict__ edges1,
    const int* __restrict__ rowptr2, const int2* __restrict__ edges2,
    float* __restrict__ outF) {
    int lane = threadIdx.x & 63;
    int n = blockIdx.x * 4 + (threadIdx.x >> 6);
    if (n >= N_NODES) return;

    float acc[8] = {0.f, 0.f, 0.f, 0.f, 0.f, 0.f, 0.f, 0.f};
    gather_row(T1, rowptr1, edges1, n, lane, acc);
    gather_row(T2, rowptr2, edges2, n, lane, acc);

    size_t o = (size_t)n * 256 + lane * 4;
    uint4 q = *(const uint4*)(Q + o);
    uint4 th = *(const uint4*)(theta + o);
    float res[8];
    res[0] = -lo16(th.x) * fast_tanh(lo16(q.x) + acc[0]);
    res[1] = -hi16(th.x) * fast_tanh(hi16(q.x) + acc[1]);
    res[2] = -lo16(th.y) * fast_tanh(lo16(q.y) + acc[2]);
    res[3] = -hi16(th.y) * fast_tanh(hi16(q.y) + acc[3]);
    res[4] = -lo16(th.z) * fast_tanh(lo16(q.z) + acc[4]);
    res[5] = -hi16(th.z) * fast_tanh(hi16(q.z) + acc[5]);
    res[6] = -lo16(th.w) * fast_tanh(lo16(q.w) + acc[6]);
    res[7] = -hi16(th.w) * fast_tanh(hi16(q.w) + acc[7]);
    int b = lane >> 3;
    int f0 = ((lane * 4) & 31) * 2;
    float* dst = outF + (size_t)b * (N_NODES * 64) + (size_t)n * 64 + f0;
    *(float4*)(dst) = make_float4(res[0], res[1], res[2], res[3]);
    *(float4*)(dst + 4) = make_float4(res[4], res[5], res[6], res[7]);
}

// ---------------- MFMA GEMM: 64 rows/block (4 waves x 16 rows), optional col-split ---
struct Slabs { const u16* p[5]; };

// MODE 0: plain (+bias1 on cols<64) -> 64-wide slabs at O1
// MODE 1: fused: col<64 sigmoid(+bias1)->O1 (64-wide); col>=64 tanh(+bias2)->O2 (128-wide)
template <int FIN, int NM, int NOUT, int NSPLIT, int MODE>
__global__ __launch_bounds__(256) void gemm_kernel(
    Slabs A, const u16* __restrict__ Bp, const float* __restrict__ bias1,
    const float* __restrict__ bias2, u16* __restrict__ O1, u16* __restrict__ O2) {
    constexpr int K = NM * FIN;
    constexpr int KS = K / 32;
    constexpr int CTT = NOUT / 16;
    constexpr int CT = CTT / NSPLIT;
    int lane = threadIdx.x & 63;
    int wave = threadIdx.x >> 6;
    int rowBase = (blockIdx.x / NSPLIT) * 64 + wave * 16;
    int ctBase = (blockIdx.x % NSPLIT) * CT;
    int mrow = lane & 15;
    int kq = lane >> 4;

    float4v acc[CT];
#pragma unroll
    for (int c = 0; c < CT; c++) acc[c] = (float4v){0.f, 0.f, 0.f, 0.f};

#pragma unroll
    for (int ks = 0; ks < KS; ks++) {
        int k = ks * 32 + kq * 8;
        int m = k / FIN;  // uniform within ks
        int koff = k % FIN;
        short8 a = *(const short8*)(A.p[m] + (size_t)(rowBase + mrow) * FIN + koff);
        short8 b[CT];
#pragma unroll
        for (int ct = 0; ct < CT; ct++)
            b[ct] = *(const short8*)(Bp + ((size_t)(ks * CTT + ctBase + ct) * 64 + lane) * 8);
#pragma unroll
        for (int ct = 0; ct < CT; ct++)
            acc[ct] = __builtin_amdgcn_mfma_f32_16x16x32_bf16(a, b[ct], acc[ct], 0, 0, 0);
    }

    int rowq = rowBase + kq * 4;
#pragma unroll
    for (int ct = 0; ct < CT; ct++) {
        int col = (ctBase + ct) * 16 + mrow;
        float bsv;
        if (MODE == 0) bsv = (col < 64) ? bias1[col] : 0.f;
        else bsv = (col < 64) ? bias1[col] : bias2[col - 64];
#pragma unroll
        for (int i = 0; i < 4; i++) {
            float v = acc[ct][i] + bsv;
            int r = rowq + i;
            if (MODE == 0) {
                O1[(size_t)(col >> 6) * ((size_t)NB * 64) + (size_t)r * 64 + (col & 63)] = f2bf(v);
            } else {
                if (col < 64) {
                    v = 1.f / (1.f + __expf(-v));
                    O1[(size_t)r * 64 + col] = f2bf(v);
                } else {
                    O2[(size_t)r * 128 + (col - 64)] = f2bf(fast_tanh(v));
                }
            }
        }
    }
}

// ---------------- launch ----------------
extern "C" void kernel_launch(void* const* d_in, const int* in_sizes, int n_in,
                              void* d_out, int out_size, void* d_ws, size_t ws_size,
                              hipStream_t stream) {
    const float* y     = (const float*)d_in[0];
    const float* W_lat = (const float*)d_in[1];
    const float* b_lat = (const float*)d_in[2];
    const float* W_units = (const float*)d_in[3];
    const float* b_units = (const float*)d_in[4];
    const float* W_final = (const float*)d_in[5];
    const float* sup1w = (const float*)d_in[6];
    const float* sup2w = (const float*)d_in[7];
    const int* rows    = (const int*)d_in[8];
    const int* cols    = (const int*)d_in[9];
    float* out = (float*)d_out;

    char* ws = (char*)d_ws;
    size_t off = 0;
    auto alloc = [&](size_t bytes) -> void* {
        void* p = ws + off;
        off += (bytes + 511) & ~(size_t)511;
        return p;
    };
    int* rowptr1 = (int*)alloc((N_NODES + 1) * 4);
    int* rowptr2 = (int*)alloc((N_NODES + 1) * 4);
    int* cnt = (int*)alloc((size_t)2 * N_NODES * 4);
    int* cnt1 = cnt;
    int* cnt2 = cnt + N_NODES;
    int* bsums = (int*)alloc(2 * SCAN_CH * 4);
    int2* edges1 = (int2*)alloc((size_t)NEDGE * 8);
    int2* edges2 = (int2*)alloc((size_t)NEDGE * 8);
    u16* bpk12 = (u16*)alloc((size_t)61440 * 2);
    u16* bpkP = (u16*)alloc((size_t)40960 * 2);
    u16* theta = (u16*)alloc((size_t)NB * 64 * 2);
    u16* S = (u16*)alloc((size_t)5 * NB * 64 * 2);  // X-series; later overlaid by Q/P slabs
    u16* H0 = (u16*)alloc((size_t)NB * 128 * 2);
    u16* T1 = (u16*)alloc((size_t)NB * 64 * 2);
    u16* T2 = (u16*)alloc((size_t)NB * 64 * 2);
    u16* P = S;  // Q/P slabs overlay S (S dead after gemm12)

    const size_t SLAB = (size_t)NB * 64;

    prep_kernel<<<10479, 256, 0, stream>>>((const float2*)y, (u32*)S, W_lat, W_units,
                                           bpk12, W_final, bpkP, cnt);
    count_kernel<<<(NEDGE + 255) / 256, 256, 0, stream>>>(rows, cols, cnt1, cnt2);
    blocksum_kernel<<<2 * SCAN_CH, 256, 0, stream>>>(cnt, bsums);
    scanmid_kernel<<<1, 128, 0, stream>>>(bsums, rowptr1, rowptr2);
    scanapply_kernel<<<2 * SCAN_CH, 256, 0, stream>>>(cnt, bsums, rowptr1, rowptr2);
    scatter_kernel<<<(NEDGE + 255) / 256, 256, 0, stream>>>(rows, cols, sup1w, sup2w,
                                                            cnt1, cnt2, edges1, edges2);

    // x-side diffusion: X1 = S1@X0, X3 = S2@X0 ; X2 = 2*S1@X1 - X0, X4 = 2*S2@X3 - X0
    const u32* S0 = (const u32*)S;
    u32* X1 = (u32*)(S + 1 * SLAB);
    u32* X2 = (u32*)(S + 2 * SLAB);
    u32* X3 = (u32*)(S + 3 * SLAB);
    u32* X4 = (u32*)(S + 4 * SLAB);
    spmm2_kernel<<<5000, 256, 0, stream>>>(S0, nullptr, X1, S0, nullptr, X3,
                                           rowptr1, edges1, rowptr2, edges2, 1.f, 0.f);
    spmm2_kernel<<<5000, 256, 0, stream>>>(X1, S0, X2, X3, S0, X4,
                                           rowptr1, edges1, rowptr2, edges2, 2.f, -1.f);

    Slabs SX;
    for (int m = 0; m < 5; m++) SX.p[m] = S + (size_t)m * SLAB;
    // fused: theta = sigmoid(X@W_lat + b_lat), H0 = tanh(X@W_units + b_units)
    gemm_kernel<64, 5, 192, 1, 1><<<1250, 256, 0, stream>>>(SX, bpk12, b_lat, b_units, theta, H0);

    // P-GEMM: [Q|P1|P2|P3|P4] = H0 @ bpkP (Q = P0-P2-P4 + b_lat), overlays S
    Slabs SH;
    SH.p[0] = H0;
    gemm_kernel<128, 1, 320, 2, 0><<<2500, 256, 0, stream>>>(SH, bpkP, b_lat, nullptr, P, nullptr);

    const u32* Q  = (const u32*)(P + 0 * SLAB);
    const u32* P1 = (const u32*)(P + 1 * SLAB);
    const u32* P2 = (const u32*)(P + 2 * SLAB);
    const u32* P3 = (const u32*)(P + 3 * SLAB);
    const u32* P4 = (const u32*)(P + 4 * SLAB);
    // T1 = P1 + 2*S1@P2 ; T2 = P3 + 2*S2@P4
    spmm2_kernel<<<5000, 256, 0, stream>>>(P2, (const u32*)P1, (u32*)T1,
                                           P4, (const u32*)P3, (u32*)T2,
                                           rowptr1, edges1, rowptr2, edges2, 2.f, 1.f);
    // out = -theta * tanh(Q + S1@T1 + S2@T2)
    spmm_final_kernel<<<2500, 256, 0, stream>>>((const u32*)T1, (const u32*)T2, Q,
                                                (const u32*)theta,
                                                rowptr1, edges1, rowptr2, edges2, out);
}